// Round 11
// baseline (301.258 us; speedup 1.0000x reference)
//
#include <hip/hip_runtime.h>
#include <stdint.h>

typedef unsigned short u16;
typedef __attribute__((ext_vector_type(8))) short short8;
typedef __attribute__((ext_vector_type(4))) float f32x4;

#define S_LEN 3072
#define D_DIM 2048
#define WIN 768
#define INV_SQRT_HD 0.08838834764831845f
#define M_SHIFT 12.0f

__device__ __forceinline__ u16 f2bf(float x) {
  union { float f; uint32_t u; } v; v.f = x;
  uint32_t r = v.u + 0x7FFFu + ((v.u >> 16) & 1u);
  return (u16)(r >> 16);
}
__device__ __forceinline__ float bf2f(u16 x) {
  union { uint32_t u; float f; } v; v.u = ((uint32_t)x) << 16;
  return v.f;
}

__device__ __forceinline__ void load_lds16(const void* g, void* l) {
  __builtin_amdgcn_global_load_lds(
      (const __attribute__((address_space(1))) void*)g,
      (__attribute__((address_space(3))) void*)l, 16, 0, 0);
}

#define MFMA16(a, b, c) __builtin_amdgcn_mfma_f32_16x16x32_bf16((a), (b), (c), 0, 0, 0)

// ---------------- fused fp32 -> bf16 convert: x + 4 weights, one launch ----------------
__global__ __launch_bounds__(256) void k_cvt_all(const float* __restrict__ x,
                                                 const float* __restrict__ w0, const float* __restrict__ w1,
                                                 const float* __restrict__ w2, const float* __restrict__ w3,
                                                 u16* __restrict__ xo,
                                                 u16* __restrict__ o0, u16* __restrict__ o1,
                                                 u16* __restrict__ o2, u16* __restrict__ o3,
                                                 int n4x, int n4w) {
  int i = blockIdx.x * 256 + threadIdx.x;
  const float* in;
  u16* out;
  int off;
  if (i < n4x) {
    in = x; out = xo; off = i;
  } else {
    int j = i - n4x;
    int seg = j / n4w;
    off = j - seg * n4w;
    in = seg == 0 ? w0 : seg == 1 ? w1 : seg == 2 ? w2 : w3;
    out = seg == 0 ? o0 : seg == 1 ? o1 : seg == 2 ? o2 : o3;
  }
  float4 v = ((const float4*)in)[off];
  ushort4 o;
  o.x = f2bf(v.x); o.y = f2bf(v.y); o.z = f2bf(v.z); o.w = f2bf(v.w);
  ((ushort4*)out)[off] = o;
}

// ---------------- 128x128 GEMM body, BK=64 single-buffer, XOR-swizzled LDS ----------------
// LDS row r (64 u16 = 8 chunks of 16B): chunk c holds global chunk c ^ (r & 7).
// Banks depend on chunk only (128B rows) -> reads hit 8 distinct 16B slots per
// quarter-wave = 2 lanes/slot (free). Barrier pairs: 32 (vs 64 at BK=32).
__device__ __forceinline__ void gemm_body64(const u16* __restrict__ A, const u16* __restrict__ B,
                                            int m0, int n0, int t, f32x4 (*acc)[4],
                                            u16* lA, u16* lB) {
  const int lane = t & 63, w = t >> 6, lo = lane & 15, g = lane >> 4;
  const int wr = w >> 1, wc = w & 1;
  const int srow = t >> 3;                 // 0..31
  const int csrc = (t & 7) ^ (srow & 7);   // inverse swizzle on SOURCE (rule #21)
  const u16* ga = A + (size_t)(m0 + srow) * D_DIM + csrc * 8;
  const u16* gb = B + (size_t)(n0 + srow) * D_DIM + csrc * 8;
  for (int k0 = 0; k0 < D_DIM; k0 += 64) {
    load_lds16(ga + k0,                       &lA[t * 8]);
    load_lds16(ga + (size_t)32 * D_DIM + k0,  &lA[2048 + t * 8]);
    load_lds16(ga + (size_t)64 * D_DIM + k0,  &lA[4096 + t * 8]);
    load_lds16(ga + (size_t)96 * D_DIM + k0,  &lA[6144 + t * 8]);
    load_lds16(gb + k0,                       &lB[t * 8]);
    load_lds16(gb + (size_t)32 * D_DIM + k0,  &lB[2048 + t * 8]);
    load_lds16(gb + (size_t)64 * D_DIM + k0,  &lB[4096 + t * 8]);
    load_lds16(gb + (size_t)96 * D_DIM + k0,  &lB[6144 + t * 8]);
    __syncthreads();
    short8 af[4][2], bfr[4][2];
#pragma unroll
    for (int m = 0; m < 4; ++m) {
      const int R = wr * 64 + m * 16 + lo;
#pragma unroll
      for (int kk = 0; kk < 2; ++kk)
        af[m][kk] = *(const short8*)&lA[R * 64 + ((((kk << 2) + g) ^ (R & 7)) << 3)];
    }
#pragma unroll
    for (int n = 0; n < 4; ++n) {
      const int R = wc * 64 + n * 16 + lo;
#pragma unroll
      for (int kk = 0; kk < 2; ++kk)
        bfr[n][kk] = *(const short8*)&lB[R * 64 + ((((kk << 2) + g) ^ (R & 7)) << 3)];
    }
#pragma unroll
    for (int m = 0; m < 4; ++m)
#pragma unroll
      for (int n = 0; n < 4; ++n) {
        acc[m][n] = MFMA16(af[m][0], bfr[n][0], acc[m][n]);
        acc[m][n] = MFMA16(af[m][1], bfr[n][1], acc[m][n]);
      }
    __syncthreads();
  }
}

// ---------------- fused QKV GEMM, A-resident XCD chunking, V written TRANSPOSED ----------------
__global__ __launch_bounds__(256) void k_gemm_qkv(const u16* __restrict__ A,
                                                  const u16* __restrict__ Bq, const u16* __restrict__ Bk,
                                                  const u16* __restrict__ Bv,
                                                  const float* __restrict__ bq, const float* __restrict__ bk,
                                                  const float* __restrict__ bv,
                                                  u16* __restrict__ Qb, u16* __restrict__ Kb,
                                                  u16* __restrict__ vT) {
  __shared__ u16 lA[128 * 64];
  __shared__ u16 lB[128 * 64];
  const int id = blockIdx.x;
  const int xcd = id & 7, local = id >> 3;   // 144 per XCD
  const int m_idx = xcd * 3 + local / 48;    // x-chunk (1.6 MB) L2-hot per XCD
  const int n_idx = local % 48;
  const int m0 = m_idx * 128;
  const int seg = n_idx >> 4, n0 = (n_idx & 15) * 128;
  const u16* B = seg == 0 ? Bq : seg == 1 ? Bk : Bv;
  const float* bias = seg == 0 ? bq : seg == 1 ? bk : bv;
  const int t = threadIdx.x;
  const int lane = t & 63, w = t >> 6, lo = lane & 15, g = lane >> 4;
  const int wr = w >> 1, wc = w & 1;
  const f32x4 zero4 = {0.f, 0.f, 0.f, 0.f};
  f32x4 acc[4][4];
#pragma unroll
  for (int m = 0; m < 4; ++m)
#pragma unroll
    for (int n = 0; n < 4; ++n) acc[m][n] = zero4;
  gemm_body64(A, B, m0, n0, t, acc, lA, lB);

  if (seg == 2) {
    // V: write transposed (vT[d][s]); 4 consecutive rows -> one 8B store.
#pragma unroll
    for (int m = 0; m < 4; ++m) {
      const int row = m0 + wr * 64 + m * 16 + 4 * g;
#pragma unroll
      for (int n = 0; n < 4; ++n) {
        const int col = n0 + wc * 64 + n * 16 + lo;
        const float bb = bias[col];
        ushort4 o;
        o.x = f2bf(acc[m][n][0] + bb);
        o.y = f2bf(acc[m][n][1] + bb);
        o.z = f2bf(acc[m][n][2] + bb);
        o.w = f2bf(acc[m][n][3] + bb);
        *(ushort4*)&vT[(size_t)col * S_LEN + row] = o;
      }
    }
  } else {
    u16* D = seg == 0 ? Qb : Kb;
#pragma unroll
    for (int m = 0; m < 4; ++m) {
      const int row = m0 + wr * 64 + m * 16 + 4 * g;
#pragma unroll
      for (int n = 0; n < 4; ++n) {
        const int col = n0 + wc * 64 + n * 16 + lo;
        const float bb = bias[col];
#pragma unroll
        for (int r = 0; r < 4; ++r)
          D[(size_t)(row + r) * 2048 + col] = f2bf(acc[m][n][r] + bb);
      }
    }
  }
}

// ---------------- WO GEMM: 384 blocks, A-resident XCD chunking, fp32 out ----------------
__global__ __launch_bounds__(256) void k_gemm_wo(const u16* __restrict__ A,
                                                 const u16* __restrict__ B,
                                                 const float* __restrict__ bias,
                                                 float* __restrict__ C) {
  __shared__ u16 lA[128 * 64];
  __shared__ u16 lB[128 * 64];
  const int id = blockIdx.x;
  const int xcd = id & 7, local = id >> 3;   // 48 per XCD
  const int m_idx = xcd * 3 + local / 16;
  const int n_idx = local % 16;
  const int m0 = m_idx * 128, n0 = n_idx * 128;
  const int t = threadIdx.x;
  const int lane = t & 63, w = t >> 6, lo = lane & 15, g = lane >> 4;
  const int wr = w >> 1, wc = w & 1;
  const f32x4 zero4 = {0.f, 0.f, 0.f, 0.f};
  f32x4 acc[4][4];
#pragma unroll
  for (int m = 0; m < 4; ++m)
#pragma unroll
    for (int n = 0; n < 4; ++n) acc[m][n] = zero4;
  gemm_body64(A, B, m0, n0, t, acc, lA, lB);
#pragma unroll
  for (int m = 0; m < 4; ++m) {
    const int row = m0 + wr * 64 + m * 16 + 4 * g;
#pragma unroll
    for (int n = 0; n < 4; ++n) {
      const int col = n0 + wc * 64 + n * 16 + lo;
      const float bb = bias[col];
#pragma unroll
      for (int r = 0; r < 4; ++r)
        C[(size_t)(row + r) * 2048 + col] = acc[m][n][r] + bb;
    }
  }
}

// ---------------- fused RMSNorm + RoPE for Q and K, one launch (grid (S,2)) ----------------
__global__ __launch_bounds__(256) void k_rms_rope2(const u16* __restrict__ Q0, const u16* __restrict__ K0,
                                                   const float* __restrict__ gq, const float* __restrict__ gk,
                                                   const float* __restrict__ cosT, const float* __restrict__ sinT,
                                                   u16* __restrict__ qo, u16* __restrict__ ko) {
  const int s = blockIdx.x, t = threadIdx.x;
  const u16* H = blockIdx.y ? K0 : Q0;
  const float* gain = blockIdx.y ? gk : gq;
  u16* out = blockIdx.y ? ko : qo;
  const short8 hv = *(const short8*)(H + (size_t)s * D_DIM + t * 8);
  float h[8];
#pragma unroll
  for (int j = 0; j < 8; ++j) h[j] = bf2f((u16)hv[j]);
  float ss = 0.f;
#pragma unroll
  for (int j = 0; j < 8; ++j) ss += h[j] * h[j];
#pragma unroll
  for (int off = 32; off > 0; off >>= 1) ss += __shfl_xor(ss, off);
  __shared__ float red[4];
  if ((t & 63) == 0) red[t >> 6] = ss;
  __syncthreads();
  ss = red[0] + red[1] + red[2] + red[3];
  const float rs = rsqrtf(ss * (1.f / D_DIM) + 1e-6f);
  const float4 g0 = *(const float4*)(gain + t * 8);
  const float4 g1 = *(const float4*)(gain + t * 8 + 4);
  float y[8];
  y[0] = h[0] * rs * g0.x; y[1] = h[1] * rs * g0.y;
  y[2] = h[2] * rs * g0.z; y[3] = h[3] * rs * g0.w;
  y[4] = h[4] * rs * g1.x; y[5] = h[5] * rs * g1.y;
  y[6] = h[6] * rs * g1.z; y[7] = h[7] * rs * g1.w;
  const int cbase = ((t * 8) & 127) >> 1;
  short8 o8;
#pragma unroll
  for (int i = 0; i < 4; ++i) {
    const float cs = cosT[s * 64 + cbase + i];
    const float sn = sinT[s * 64 + cbase + i];
    const float yr = y[2 * i] * cs - y[2 * i + 1] * sn;
    const float yi = y[2 * i] * sn + y[2 * i + 1] * cs;
    o8[2 * i] = (short)f2bf(yr);
    o8[2 * i + 1] = (short)f2bf(yi);
  }
  *(short8*)(out + (size_t)s * D_DIM + t * 8) = o8;
}

// ---------------- banded flash attention: QBLK=128, double-buffered staging ----------------
__global__ __launch_bounds__(256, 3) void k_attn5(const u16* __restrict__ Q,
                                                  const u16* __restrict__ Kmat,
                                                  const u16* __restrict__ Vt,
                                                  u16* __restrict__ Oa,
                                                  u16* __restrict__ Ob,
                                                  float* __restrict__ lbuf) {
  const int qt = blockIdx.x, h = blockIdx.y, z = blockIdx.z;
  const int t = threadIdx.x, w = t >> 6, lane = t & 63, lo = lane & 15, g = lane >> 4;
  const int q0 = qt * 128;
  const int wrow = q0 + w * 32;
  const size_t hoff = (size_t)h * 128;

  __shared__ u16 lK[2][32 * 128];
  __shared__ u16 lV[2][128 * 32];
  __shared__ u16 ldsp[4][32][40];

  short8 qf[2][4];
#pragma unroll
  for (int m = 0; m < 2; ++m) {
    const u16* qp = Q + (size_t)(wrow + m * 16 + lo) * D_DIM + hoff + g * 8;
#pragma unroll
    for (int c = 0; c < 4; ++c) qf[m][c] = *(const short8*)(qp + c * 32);
  }

  const f32x4 zero4 = {0.f, 0.f, 0.f, 0.f};
  f32x4 oacc[2][8];
#pragma unroll
  for (int m = 0; m < 2; ++m)
#pragma unroll
    for (int ct = 0; ct < 8; ++ct) oacc[m][ct] = zero4;
  float lrun[2][4] = {{0.f, 0.f, 0.f, 0.f}, {0.f, 0.f, 0.f, 0.f}};

  int jlo = q0 - WIN; if (jlo < 0) jlo = 0;
  int jhi = q0 + 127 + WIN + 1; if (jhi > S_LEN) jhi = S_LEN;
  const int NT = (jhi - jlo) >> 5;
  const int it0 = z * (NT >> 1), it1 = it0 + (NT >> 1);

  const int krow = t >> 4,          kch  = (t & 15) ^ (krow & 7);
  const int krow1 = (t + 256) >> 4, kch1 = (t & 15) ^ (krow1 & 7);
  const int vrow = t >> 2,          vch  = (t & 3) ^ ((vrow >> 1) & 3);
  const int vrow1 = (t + 256) >> 2, vch1 = (t & 3) ^ ((vrow1 >> 1) & 3);

#define STAGE5(buf, jj)                                                                              \
  do {                                                                                               \
    load_lds16(Kmat + (size_t)((jj) + krow) * D_DIM + hoff + (kch << 3), &lK[buf][t * 8]);           \
    load_lds16(Kmat + (size_t)((jj) + krow1) * D_DIM + hoff + (kch1 << 3), &lK[buf][(t + 256) * 8]); \
    load_lds16(Vt + (size_t)(hoff + vrow) * S_LEN + (jj) + (vch << 3), &lV[buf][t * 8]);             \
    load_lds16(Vt + (size_t)(hoff + vrow1) * S_LEN + (jj) + (vch1 << 3), &lV[buf][(t + 256) * 8]);   \
  } while (0)

  STAGE5(0, jlo + (it0 << 5));
  __syncthreads();
  int cur = 0;
  for (int it = it0; it < it1; ++it) {
    const int j0 = jlo + (it << 5);
    if (it + 1 < it1) STAGE5(cur ^ 1, j0 + 32);

    f32x4 sc[2][2];
    sc[0][0] = zero4; sc[0][1] = zero4; sc[1][0] = zero4; sc[1][1] = zero4;
#pragma unroll
    for (int half = 0; half < 2; ++half) {
#pragma unroll
      for (int c = 0; c < 4; ++c) {
        const short8 kf = *(const short8*)
            &lK[cur][(half * 16 + lo) * 128 + (((g + 4 * c) ^ (lo & 7)) << 3)];
        sc[0][half] = MFMA16(qf[0][c], kf, sc[0][half]);
        sc[1][half] = MFMA16(qf[1][c], kf, sc[1][half]);
      }
    }

    const int dq = j0 - q0;
    const bool interior = (dq >= -640) && (dq <= 736);
#pragma unroll
    for (int m = 0; m < 2; ++m) {
#pragma unroll
      for (int r = 0; r < 4; ++r) {
        float a0 = fmaf(sc[m][0][r], INV_SQRT_HD, -M_SHIFT);
        float a1 = fmaf(sc[m][1][r], INV_SQRT_HD, -M_SHIFT);
        if (!interior) {
          const int dk = j0 + lo - (wrow + m * 16 + 4 * g + r);
          if (dk < -WIN || dk > WIN) a0 = -3e38f;
          if (dk + 16 < -WIN || dk + 16 > WIN) a1 = -3e38f;
        }
        const float p0 = __expf(a0);
        const float p1 = __expf(a1);
        lrun[m][r] += p0 + p1;
        ldsp[w][m * 16 + 4 * g + r][lo] = f2bf(p0);
        ldsp[w][m * 16 + 4 * g + r][16 + lo] = f2bf(p1);
      }
    }

    const short8 pf0 = *(const short8*)&ldsp[w][lo][g * 8];
    const short8 pf1 = *(const short8*)&ldsp[w][16 + lo][g * 8];
#pragma unroll
    for (int ct = 0; ct < 8; ++ct) {
      const short8 vf = *(const short8*)
          &lV[cur][(ct * 16 + lo) * 32 + ((g ^ ((lo >> 1) & 3)) << 3)];
      oacc[0][ct] = MFMA16(pf0, vf, oacc[0][ct]);
      oacc[1][ct] = MFMA16(pf1, vf, oacc[1][ct]);
    }
    __syncthreads();
    cur ^= 1;
  }
#undef STAGE5

#pragma unroll
  for (int off = 8; off > 0; off >>= 1)
#pragma unroll
    for (int m = 0; m < 2; ++m)
#pragma unroll
      for (int r = 0; r < 4; ++r) lrun[m][r] += __shfl_xor(lrun[m][r], off);

  u16* Op = z ? Ob : Oa;
#pragma unroll
  for (int m = 0; m < 2; ++m)
#pragma unroll
    for (int r = 0; r < 4; ++r) {
      const int row = wrow + m * 16 + 4 * g + r;
#pragma unroll
      for (int ct = 0; ct < 8; ++ct)
        Op[(size_t)row * D_DIM + hoff + ct * 16 + lo] = f2bf(oacc[m][ct][r]);
      if (lo == 0) lbuf[(size_t)z * S_LEN * 16 + (size_t)row * 16 + h] = lrun[m][r];
    }
}

// ---------------- combine: out = (Oa + Ob) / (la + lb), bf16 ----------------
__global__ __launch_bounds__(256) void k_combine(const u16* __restrict__ Oa,
                                                 const u16* __restrict__ Ob,
                                                 const float* __restrict__ lbuf,
                                                 u16* __restrict__ out) {
  const int i = blockIdx.x * 256 + threadIdx.x;
  const int s = i >> 8, d8 = (i & 255) * 8, h = d8 >> 7;
  const float la = lbuf[(size_t)s * 16 + h];
  const float lb = lbuf[(size_t)S_LEN * 16 + (size_t)s * 16 + h];
  const float inv = 1.f / (la + lb);
  const size_t base = (size_t)s * D_DIM + d8;
  const short8 a = *(const short8*)(Oa + base);
  const short8 b = *(const short8*)(Ob + base);
  short8 o;
#pragma unroll
  for (int j = 0; j < 8; ++j)
    o[j] = (short)f2bf((bf2f((u16)a[j]) + bf2f((u16)b[j])) * inv);
  *(short8*)(out + base) = o;
}

extern "C" void kernel_launch(void* const* d_in, const int* in_sizes, int n_in,
                              void* d_out, int out_size, void* d_ws, size_t ws_size,
                              hipStream_t stream) {
  const float* x    = (const float*)d_in[0];
  const float* wq   = (const float*)d_in[1];
  const float* bq   = (const float*)d_in[2];
  const float* wk   = (const float*)d_in[3];
  const float* bk   = (const float*)d_in[4];
  const float* wv   = (const float*)d_in[5];
  const float* bv   = (const float*)d_in[6];
  const float* wo   = (const float*)d_in[7];
  const float* bo   = (const float*)d_in[8];
  const float* gq   = (const float*)d_in[9];
  const float* gk   = (const float*)d_in[10];
  const float* cosT = (const float*)d_in[11];
  const float* sinT = (const float*)d_in[12];

  char* ws = (char*)d_ws;
  const size_t WB = (size_t)D_DIM * D_DIM * 2;  // 8.4 MB
  const size_t XB = (size_t)S_LEN * D_DIM * 2;  // 12.6 MB
  u16*   wq_bf = (u16*)(ws);
  u16*   wk_bf = (u16*)(ws + WB);
  u16*   wv_bf = (u16*)(ws + 2 * WB);
  u16*   wo_bf = (u16*)(ws + 3 * WB);
  u16*   x_bf  = (u16*)(ws + 4 * WB);
  u16*   Q0b   = (u16*)(ws + 4 * WB + XB);
  u16*   K0b   = (u16*)(ws + 4 * WB + 2 * XB);
  u16*   vT    = (u16*)(ws + 4 * WB + 3 * XB);   // written transposed by QKV GEMM
  float* lbuf  = (float*)(ws + 4 * WB + 4 * XB); // 2*S*16 fp32
  // stream-ordered reuse:
  u16* q_bf = x_bf;          // x_bf dead after QKV GEMM
  u16* k_bf = wq_bf;         // wq/wk/wv bf16 dead after QKV GEMM
  u16* Ob   = K0b;           // K0b dead after rms_rope2
  u16* Oa   = (u16*)d_out;   // scratch; overwritten by final GEMM
  u16* attn = Q0b;           // Q0b dead after rms_rope2

  const int nw4 = (D_DIM * D_DIM) / 4;
  const int nx4 = (S_LEN * D_DIM) / 4;
  k_cvt_all<<<(nx4 + 4 * nw4) / 256, 256, 0, stream>>>(
      x, wq, wk, wv, wo, x_bf, wq_bf, wk_bf, wv_bf, wo_bf, nx4, nw4);

  k_gemm_qkv<<<1152, 256, 0, stream>>>(x_bf, wq_bf, wk_bf, wv_bf, bq, bk, bv, Q0b, K0b, vT);

  k_rms_rope2<<<dim3(S_LEN, 2), 256, 0, stream>>>(Q0b, K0b, gq, gk, cosT, sinT, q_bf, k_bf);

  k_attn5<<<dim3(S_LEN / 128, 16, 2), 256, 0, stream>>>(q_bf, k_bf, vT, Oa, Ob, lbuf);
  k_combine<<<(S_LEN * D_DIM / 8) / 256, 256, 0, stream>>>(Oa, Ob, lbuf, attn);

  k_gemm_wo<<<384, 256, 0, stream>>>(attn, wo_bf, bo, (float*)d_out);
}

// Round 12
// 275.963 us; speedup vs baseline: 1.0917x; 1.0917x over previous
//
#include <hip/hip_runtime.h>
#include <stdint.h>

typedef unsigned short u16;
typedef __attribute__((ext_vector_type(8))) short short8;
typedef __attribute__((ext_vector_type(4))) float f32x4;

#define S_LEN 3072
#define D_DIM 2048
#define WIN 768
#define INV_SQRT_HD 0.08838834764831845f
#define M_SHIFT 12.0f

__device__ __forceinline__ u16 f2bf(float x) {
  union { float f; uint32_t u; } v; v.f = x;
  uint32_t r = v.u + 0x7FFFu + ((v.u >> 16) & 1u);
  return (u16)(r >> 16);
}
__device__ __forceinline__ float bf2f(u16 x) {
  union { uint32_t u; float f; } v; v.u = ((uint32_t)x) << 16;
  return v.f;
}

__device__ __forceinline__ void load_lds16(const void* g, void* l) {
  __builtin_amdgcn_global_load_lds(
      (const __attribute__((address_space(1))) void*)g,
      (__attribute__((address_space(3))) void*)l, 16, 0, 0);
}

#define MFMA16(a, b, c) __builtin_amdgcn_mfma_f32_16x16x32_bf16((a), (b), (c), 0, 0, 0)

// ---------------- fused fp32 -> bf16 convert: x + 4 weights, one launch ----------------
__global__ __launch_bounds__(256) void k_cvt_all(const float* __restrict__ x,
                                                 const float* __restrict__ w0, const float* __restrict__ w1,
                                                 const float* __restrict__ w2, const float* __restrict__ w3,
                                                 u16* __restrict__ xo,
                                                 u16* __restrict__ o0, u16* __restrict__ o1,
                                                 u16* __restrict__ o2, u16* __restrict__ o3,
                                                 int n4x, int n4w) {
  int i = blockIdx.x * 256 + threadIdx.x;
  const float* in;
  u16* out;
  int off;
  if (i < n4x) {
    in = x; out = xo; off = i;
  } else {
    int j = i - n4x;
    int seg = j / n4w;
    off = j - seg * n4w;
    in = seg == 0 ? w0 : seg == 1 ? w1 : seg == 2 ? w2 : w3;
    out = seg == 0 ? o0 : seg == 1 ? o1 : seg == 2 ? o2 : o3;
  }
  float4 v = ((const float4*)in)[off];
  ushort4 o;
  o.x = f2bf(v.x); o.y = f2bf(v.y); o.z = f2bf(v.z); o.w = f2bf(v.w);
  ((ushort4*)out)[off] = o;
}

// ---------------- 128x128 GEMM body, BK=32 (m97 pattern, proven 123us QKV) ----------------
__device__ __forceinline__ void gemm_body(const u16* __restrict__ A, const u16* __restrict__ B,
                                          int m0, int n0, int t, f32x4 (*acc)[4],
                                          u16* lA, u16* lB) {
  const int lane = t & 63, w = t >> 6, lo = lane & 15, g = lane >> 4;
  const int wr = w >> 1, wc = w & 1;
  const int srow = t >> 2;
  const int sch = (t & 3) ^ ((srow ^ (srow >> 3)) & 3);
  const u16* ga = A + (size_t)(m0 + srow) * D_DIM + sch * 8;
  const u16* gb = B + (size_t)(n0 + srow) * D_DIM + sch * 8;
  for (int k0 = 0; k0 < D_DIM; k0 += 32) {
    load_lds16(ga + k0, &lA[t * 8]);
    load_lds16(ga + (size_t)64 * D_DIM + k0, &lA[2048 + t * 8]);
    load_lds16(gb + k0, &lB[t * 8]);
    load_lds16(gb + (size_t)64 * D_DIM + k0, &lB[2048 + t * 8]);
    __syncthreads();
    short8 af[4], bfr[4];
#pragma unroll
    for (int m = 0; m < 4; ++m) {
      const int R = wr * 64 + m * 16 + lo;
      af[m] = *(const short8*)&lA[R * 32 + ((g ^ ((R ^ (R >> 3)) & 3)) << 3)];
    }
#pragma unroll
    for (int n = 0; n < 4; ++n) {
      const int R = wc * 64 + n * 16 + lo;
      bfr[n] = *(const short8*)&lB[R * 32 + ((g ^ ((R ^ (R >> 3)) & 3)) << 3)];
    }
#pragma unroll
    for (int m = 0; m < 4; ++m)
#pragma unroll
      for (int n = 0; n < 4; ++n) acc[m][n] = MFMA16(af[m], bfr[n], acc[m][n]);
    __syncthreads();
  }
}

// ---------------- fused QKV GEMM, A-resident XCD chunking, V written TRANSPOSED ----------------
__global__ __launch_bounds__(256) void k_gemm_qkv(const u16* __restrict__ A,
                                                  const u16* __restrict__ Bq, const u16* __restrict__ Bk,
                                                  const u16* __restrict__ Bv,
                                                  const float* __restrict__ bq, const float* __restrict__ bk,
                                                  const float* __restrict__ bv,
                                                  u16* __restrict__ Qb, u16* __restrict__ Kb,
                                                  u16* __restrict__ vT) {
  __shared__ u16 lA[128 * 32];
  __shared__ u16 lB[128 * 32];
  const int id = blockIdx.x;
  const int xcd = id & 7, local = id >> 3;   // 144 per XCD
  const int m_idx = xcd * 3 + local / 48;    // x-chunk (1.6 MB) L2-hot per XCD
  const int n_idx = local % 48;
  const int m0 = m_idx * 128;
  const int seg = n_idx >> 4, n0 = (n_idx & 15) * 128;
  const u16* B = seg == 0 ? Bq : seg == 1 ? Bk : Bv;
  const float* bias = seg == 0 ? bq : seg == 1 ? bk : bv;
  const int t = threadIdx.x;
  const int lane = t & 63, w = t >> 6, lo = lane & 15, g = lane >> 4;
  const int wr = w >> 1, wc = w & 1;
  const f32x4 zero4 = {0.f, 0.f, 0.f, 0.f};
  f32x4 acc[4][4];
#pragma unroll
  for (int m = 0; m < 4; ++m)
#pragma unroll
    for (int n = 0; n < 4; ++n) acc[m][n] = zero4;
  gemm_body(A, B, m0, n0, t, acc, lA, lB);

  if (seg == 2) {
    // V: write transposed (vT[d][s]); 4 consecutive s-rows -> one 8B store.
#pragma unroll
    for (int m = 0; m < 4; ++m) {
      const int row = m0 + wr * 64 + m * 16 + 4 * g;
#pragma unroll
      for (int n = 0; n < 4; ++n) {
        const int col = n0 + wc * 64 + n * 16 + lo;
        const float bb = bias[col];
        ushort4 o;
        o.x = f2bf(acc[m][n][0] + bb);
        o.y = f2bf(acc[m][n][1] + bb);
        o.z = f2bf(acc[m][n][2] + bb);
        o.w = f2bf(acc[m][n][3] + bb);
        *(ushort4*)&vT[(size_t)col * S_LEN + row] = o;
      }
    }
  } else {
    u16* D = seg == 0 ? Qb : Kb;
#pragma unroll
    for (int m = 0; m < 4; ++m) {
      const int row = m0 + wr * 64 + m * 16 + 4 * g;
#pragma unroll
      for (int n = 0; n < 4; ++n) {
        const int col = n0 + wc * 64 + n * 16 + lo;
        const float bb = bias[col];
#pragma unroll
        for (int r = 0; r < 4; ++r)
          D[(size_t)(row + r) * 2048 + col] = f2bf(acc[m][n][r] + bb);
      }
    }
  }
}

// ---------------- WO GEMM: 384 blocks, A-resident XCD chunking, fp32 out ----------------
__global__ __launch_bounds__(256) void k_gemm_wo(const u16* __restrict__ A,
                                                 const u16* __restrict__ B,
                                                 const float* __restrict__ bias,
                                                 float* __restrict__ C) {
  __shared__ u16 lA[128 * 32];
  __shared__ u16 lB[128 * 32];
  const int id = blockIdx.x;
  const int xcd = id & 7, local = id >> 3;   // 48 per XCD
  const int m_idx = xcd * 3 + local / 16;
  const int n_idx = local % 16;
  const int m0 = m_idx * 128, n0 = n_idx * 128;
  const int t = threadIdx.x;
  const int lane = t & 63, w = t >> 6, lo = lane & 15, g = lane >> 4;
  const int wr = w >> 1, wc = w & 1;
  const f32x4 zero4 = {0.f, 0.f, 0.f, 0.f};
  f32x4 acc[4][4];
#pragma unroll
  for (int m = 0; m < 4; ++m)
#pragma unroll
    for (int n = 0; n < 4; ++n) acc[m][n] = zero4;
  gemm_body(A, B, m0, n0, t, acc, lA, lB);
#pragma unroll
  for (int m = 0; m < 4; ++m) {
    const int row = m0 + wr * 64 + m * 16 + 4 * g;
#pragma unroll
    for (int n = 0; n < 4; ++n) {
      const int col = n0 + wc * 64 + n * 16 + lo;
      const float bb = bias[col];
#pragma unroll
      for (int r = 0; r < 4; ++r)
        C[(size_t)(row + r) * 2048 + col] = acc[m][n][r] + bb;
    }
  }
}

// ---------------- fused RMSNorm + RoPE for Q and K, one launch (grid (S,2)) ----------------
__global__ __launch_bounds__(256) void k_rms_rope2(const u16* __restrict__ Q0, const u16* __restrict__ K0,
                                                   const float* __restrict__ gq, const float* __restrict__ gk,
                                                   const float* __restrict__ cosT, const float* __restrict__ sinT,
                                                   u16* __restrict__ qo, u16* __restrict__ ko) {
  const int s = blockIdx.x, t = threadIdx.x;
  const u16* H = blockIdx.y ? K0 : Q0;
  const float* gain = blockIdx.y ? gk : gq;
  u16* out = blockIdx.y ? ko : qo;
  const short8 hv = *(const short8*)(H + (size_t)s * D_DIM + t * 8);
  float h[8];
#pragma unroll
  for (int j = 0; j < 8; ++j) h[j] = bf2f((u16)hv[j]);
  float ss = 0.f;
#pragma unroll
  for (int j = 0; j < 8; ++j) ss += h[j] * h[j];
#pragma unroll
  for (int off = 32; off > 0; off >>= 1) ss += __shfl_xor(ss, off);
  __shared__ float red[4];
  if ((t & 63) == 0) red[t >> 6] = ss;
  __syncthreads();
  ss = red[0] + red[1] + red[2] + red[3];
  const float rs = rsqrtf(ss * (1.f / D_DIM) + 1e-6f);
  const float4 g0 = *(const float4*)(gain + t * 8);
  const float4 g1 = *(const float4*)(gain + t * 8 + 4);
  float y[8];
  y[0] = h[0] * rs * g0.x; y[1] = h[1] * rs * g0.y;
  y[2] = h[2] * rs * g0.z; y[3] = h[3] * rs * g0.w;
  y[4] = h[4] * rs * g1.x; y[5] = h[5] * rs * g1.y;
  y[6] = h[6] * rs * g1.z; y[7] = h[7] * rs * g1.w;
  const int cbase = ((t * 8) & 127) >> 1;
  short8 o8;
#pragma unroll
  for (int i = 0; i < 4; ++i) {
    const float cs = cosT[s * 64 + cbase + i];
    const float sn = sinT[s * 64 + cbase + i];
    const float yr = y[2 * i] * cs - y[2 * i + 1] * sn;
    const float yi = y[2 * i] * sn + y[2 * i + 1] * cs;
    o8[2 * i] = (short)f2bf(yr);
    o8[2 * i + 1] = (short)f2bf(yi);
  }
  *(short8*)(out + (size_t)s * D_DIM + t * 8) = o8;
}

// ---------------- banded flash attention: QBLK=128, double-buffered staging ----------------
__global__ __launch_bounds__(256, 3) void k_attn5(const u16* __restrict__ Q,
                                                  const u16* __restrict__ Kmat,
                                                  const u16* __restrict__ Vt,
                                                  u16* __restrict__ Oa,
                                                  u16* __restrict__ Ob,
                                                  float* __restrict__ lbuf) {
  const int qt = blockIdx.x, h = blockIdx.y, z = blockIdx.z;
  const int t = threadIdx.x, w = t >> 6, lane = t & 63, lo = lane & 15, g = lane >> 4;
  const int q0 = qt * 128;
  const int wrow = q0 + w * 32;
  const size_t hoff = (size_t)h * 128;

  __shared__ u16 lK[2][32 * 128];
  __shared__ u16 lV[2][128 * 32];
  __shared__ u16 ldsp[4][32][40];

  short8 qf[2][4];
#pragma unroll
  for (int m = 0; m < 2; ++m) {
    const u16* qp = Q + (size_t)(wrow + m * 16 + lo) * D_DIM + hoff + g * 8;
#pragma unroll
    for (int c = 0; c < 4; ++c) qf[m][c] = *(const short8*)(qp + c * 32);
  }

  const f32x4 zero4 = {0.f, 0.f, 0.f, 0.f};
  f32x4 oacc[2][8];
#pragma unroll
  for (int m = 0; m < 2; ++m)
#pragma unroll
    for (int ct = 0; ct < 8; ++ct) oacc[m][ct] = zero4;
  float lrun[2][4] = {{0.f, 0.f, 0.f, 0.f}, {0.f, 0.f, 0.f, 0.f}};

  int jlo = q0 - WIN; if (jlo < 0) jlo = 0;
  int jhi = q0 + 127 + WIN + 1; if (jhi > S_LEN) jhi = S_LEN;
  const int NT = (jhi - jlo) >> 5;
  const int it0 = z * (NT >> 1), it1 = it0 + (NT >> 1);

  const int krow = t >> 4,          kch  = (t & 15) ^ (krow & 7);
  const int krow1 = (t + 256) >> 4, kch1 = (t & 15) ^ (krow1 & 7);
  const int vrow = t >> 2,          vch  = (t & 3) ^ ((vrow >> 1) & 3);
  const int vrow1 = (t + 256) >> 2, vch1 = (t & 3) ^ ((vrow1 >> 1) & 3);

#define STAGE5(buf, jj)                                                                              \
  do {                                                                                               \
    load_lds16(Kmat + (size_t)((jj) + krow) * D_DIM + hoff + (kch << 3), &lK[buf][t * 8]);           \
    load_lds16(Kmat + (size_t)((jj) + krow1) * D_DIM + hoff + (kch1 << 3), &lK[buf][(t + 256) * 8]); \
    load_lds16(Vt + (size_t)(hoff + vrow) * S_LEN + (jj) + (vch << 3), &lV[buf][t * 8]);             \
    load_lds16(Vt + (size_t)(hoff + vrow1) * S_LEN + (jj) + (vch1 << 3), &lV[buf][(t + 256) * 8]);   \
  } while (0)

  STAGE5(0, jlo + (it0 << 5));
  __syncthreads();
  int cur = 0;
  for (int it = it0; it < it1; ++it) {
    const int j0 = jlo + (it << 5);
    if (it + 1 < it1) STAGE5(cur ^ 1, j0 + 32);

    f32x4 sc[2][2];
    sc[0][0] = zero4; sc[0][1] = zero4; sc[1][0] = zero4; sc[1][1] = zero4;
#pragma unroll
    for (int half = 0; half < 2; ++half) {
#pragma unroll
      for (int c = 0; c < 4; ++c) {
        const short8 kf = *(const short8*)
            &lK[cur][(half * 16 + lo) * 128 + (((g + 4 * c) ^ (lo & 7)) << 3)];
        sc[0][half] = MFMA16(qf[0][c], kf, sc[0][half]);
        sc[1][half] = MFMA16(qf[1][c], kf, sc[1][half]);
      }
    }

    const int dq = j0 - q0;
    const bool interior = (dq >= -640) && (dq <= 736);
#pragma unroll
    for (int m = 0; m < 2; ++m) {
#pragma unroll
      for (int r = 0; r < 4; ++r) {
        float a0 = fmaf(sc[m][0][r], INV_SQRT_HD, -M_SHIFT);
        float a1 = fmaf(sc[m][1][r], INV_SQRT_HD, -M_SHIFT);
        if (!interior) {
          const int dk = j0 + lo - (wrow + m * 16 + 4 * g + r);
          if (dk < -WIN || dk > WIN) a0 = -3e38f;
          if (dk + 16 < -WIN || dk + 16 > WIN) a1 = -3e38f;
        }
        const float p0 = __expf(a0);
        const float p1 = __expf(a1);
        lrun[m][r] += p0 + p1;
        ldsp[w][m * 16 + 4 * g + r][lo] = f2bf(p0);
        ldsp[w][m * 16 + 4 * g + r][16 + lo] = f2bf(p1);
      }
    }

    const short8 pf0 = *(const short8*)&ldsp[w][lo][g * 8];
    const short8 pf1 = *(const short8*)&ldsp[w][16 + lo][g * 8];
#pragma unroll
    for (int ct = 0; ct < 8; ++ct) {
      const short8 vf = *(const short8*)
          &lV[cur][(ct * 16 + lo) * 32 + ((g ^ ((lo >> 1) & 3)) << 3)];
      oacc[0][ct] = MFMA16(pf0, vf, oacc[0][ct]);
      oacc[1][ct] = MFMA16(pf1, vf, oacc[1][ct]);
    }
    __syncthreads();
    cur ^= 1;
  }
#undef STAGE5

#pragma unroll
  for (int off = 8; off > 0; off >>= 1)
#pragma unroll
    for (int m = 0; m < 2; ++m)
#pragma unroll
      for (int r = 0; r < 4; ++r) lrun[m][r] += __shfl_xor(lrun[m][r], off);

  u16* Op = z ? Ob : Oa;
#pragma unroll
  for (int m = 0; m < 2; ++m)
#pragma unroll
    for (int r = 0; r < 4; ++r) {
      const int row = wrow + m * 16 + 4 * g + r;
#pragma unroll
      for (int ct = 0; ct < 8; ++ct)
        Op[(size_t)row * D_DIM + hoff + ct * 16 + lo] = f2bf(oacc[m][ct][r]);
      if (lo == 0) lbuf[(size_t)z * S_LEN * 16 + (size_t)row * 16 + h] = lrun[m][r];
    }
}

// ---------------- combine: out = (Oa + Ob) / (la + lb), bf16 ----------------
__global__ __launch_bounds__(256) void k_combine(const u16* __restrict__ Oa,
                                                 const u16* __restrict__ Ob,
                                                 const float* __restrict__ lbuf,
                                                 u16* __restrict__ out) {
  const int i = blockIdx.x * 256 + threadIdx.x;
  const int s = i >> 8, d8 = (i & 255) * 8, h = d8 >> 7;
  const float la = lbuf[(size_t)s * 16 + h];
  const float lb = lbuf[(size_t)S_LEN * 16 + (size_t)s * 16 + h];
  const float inv = 1.f / (la + lb);
  const size_t base = (size_t)s * D_DIM + d8;
  const short8 a = *(const short8*)(Oa + base);
  const short8 b = *(const short8*)(Ob + base);
  short8 o;
#pragma unroll
  for (int j = 0; j < 8; ++j)
    o[j] = (short)f2bf((bf2f((u16)a[j]) + bf2f((u16)b[j])) * inv);
  *(short8*)(out + base) = o;
}

extern "C" void kernel_launch(void* const* d_in, const int* in_sizes, int n_in,
                              void* d_out, int out_size, void* d_ws, size_t ws_size,
                              hipStream_t stream) {
  const float* x    = (const float*)d_in[0];
  const float* wq   = (const float*)d_in[1];
  const float* bq   = (const float*)d_in[2];
  const float* wk   = (const float*)d_in[3];
  const float* bk   = (const float*)d_in[4];
  const float* wv   = (const float*)d_in[5];
  const float* bv   = (const float*)d_in[6];
  const float* wo   = (const float*)d_in[7];
  const float* bo   = (const float*)d_in[8];
  const float* gq   = (const float*)d_in[9];
  const float* gk   = (const float*)d_in[10];
  const float* cosT = (const float*)d_in[11];
  const float* sinT = (const float*)d_in[12];

  char* ws = (char*)d_ws;
  const size_t WB = (size_t)D_DIM * D_DIM * 2;  // 8.4 MB
  const size_t XB = (size_t)S_LEN * D_DIM * 2;  // 12.6 MB
  u16*   wq_bf = (u16*)(ws);
  u16*   wk_bf = (u16*)(ws + WB);
  u16*   wv_bf = (u16*)(ws + 2 * WB);
  u16*   wo_bf = (u16*)(ws + 3 * WB);
  u16*   x_bf  = (u16*)(ws + 4 * WB);
  u16*   Q0b   = (u16*)(ws + 4 * WB + XB);
  u16*   K0b   = (u16*)(ws + 4 * WB + 2 * XB);
  u16*   vT    = (u16*)(ws + 4 * WB + 3 * XB);   // written transposed by QKV GEMM
  float* lbuf  = (float*)(ws + 4 * WB + 4 * XB); // 2*S*16 fp32
  // stream-ordered reuse:
  u16* q_bf = x_bf;          // x_bf dead after QKV GEMM
  u16* k_bf = wq_bf;         // wq/wk/wv bf16 dead after QKV GEMM
  u16* Ob   = K0b;           // K0b dead after rms_rope2
  u16* Oa   = (u16*)d_out;   // scratch; overwritten by final GEMM
  u16* attn = Q0b;           // Q0b dead after rms_rope2

  const int nw4 = (D_DIM * D_DIM) / 4;
  const int nx4 = (S_LEN * D_DIM) / 4;
  k_cvt_all<<<(nx4 + 4 * nw4) / 256, 256, 0, stream>>>(
      x, wq, wk, wv, wo, x_bf, wq_bf, wk_bf, wv_bf, wo_bf, nx4, nw4);

  k_gemm_qkv<<<1152, 256, 0, stream>>>(x_bf, wq_bf, wk_bf, wv_bf, bq, bk, bv, Q0b, K0b, vT);

  k_rms_rope2<<<dim3(S_LEN, 2), 256, 0, stream>>>(Q0b, K0b, gq, gk, cosT, sinT, q_bf, k_bf);

  k_attn5<<<dim3(S_LEN / 128, 16, 2), 256, 0, stream>>>(q_bf, k_bf, vT, Oa, Ob, lbuf);
  k_combine<<<(S_LEN * D_DIM / 8) / 256, 256, 0, stream>>>(Oa, Ob, lbuf, attn);

  k_gemm_wo<<<384, 256, 0, stream>>>(attn, wo_bf, bo, (float*)d_out);
}

// Round 13
// 255.986 us; speedup vs baseline: 1.1769x; 1.0780x over previous
//
#include <hip/hip_runtime.h>
#include <stdint.h>

typedef unsigned short u16;
typedef __attribute__((ext_vector_type(8))) short short8;
typedef __attribute__((ext_vector_type(4))) float f32x4;

#define S_LEN 3072
#define D_DIM 2048
#define WIN 768
#define INV_SQRT_HD 0.08838834764831845f
#define M_SHIFT 12.0f

__device__ __forceinline__ u16 f2bf(float x) {
  union { float f; uint32_t u; } v; v.f = x;
  uint32_t r = v.u + 0x7FFFu + ((v.u >> 16) & 1u);
  return (u16)(r >> 16);
}
__device__ __forceinline__ float bf2f(u16 x) {
  union { uint32_t u; float f; } v; v.u = ((uint32_t)x) << 16;
  return v.f;
}

__device__ __forceinline__ void load_lds16(const void* g, void* l) {
  __builtin_amdgcn_global_load_lds(
      (const __attribute__((address_space(1))) void*)g,
      (__attribute__((address_space(3))) void*)l, 16, 0, 0);
}

#define MFMA16(a, b, c) __builtin_amdgcn_mfma_f32_16x16x32_bf16((a), (b), (c), 0, 0, 0)

// ---------------- fused fp32 -> bf16 convert: x + 4 weights, one launch ----------------
__global__ __launch_bounds__(256) void k_cvt_all(const float* __restrict__ x,
                                                 const float* __restrict__ w0, const float* __restrict__ w1,
                                                 const float* __restrict__ w2, const float* __restrict__ w3,
                                                 u16* __restrict__ xo,
                                                 u16* __restrict__ o0, u16* __restrict__ o1,
                                                 u16* __restrict__ o2, u16* __restrict__ o3,
                                                 int n4x, int n4w) {
  int i = blockIdx.x * 256 + threadIdx.x;
  const float* in;
  u16* out;
  int off;
  if (i < n4x) {
    in = x; out = xo; off = i;
  } else {
    int j = i - n4x;
    int seg = j / n4w;
    off = j - seg * n4w;
    in = seg == 0 ? w0 : seg == 1 ? w1 : seg == 2 ? w2 : w3;
    out = seg == 0 ? o0 : seg == 1 ? o1 : seg == 2 ? o2 : o3;
  }
  float4 v = ((const float4*)in)[off];
  ushort4 o;
  o.x = f2bf(v.x); o.y = f2bf(v.y); o.z = f2bf(v.z); o.w = f2bf(v.w);
  ((ushort4*)out)[off] = o;
}

// ---------------- 128x128 GEMM body, BK=32 (m97 pattern; proven 123us QKV) ----------------
__device__ __forceinline__ void gemm_body(const u16* __restrict__ A, const u16* __restrict__ B,
                                          int m0, int n0, int t, f32x4 (*acc)[4],
                                          u16* lA, u16* lB) {
  const int lane = t & 63, w = t >> 6, lo = lane & 15, g = lane >> 4;
  const int wr = w >> 1, wc = w & 1;
  const int srow = t >> 2;
  const int sch = (t & 3) ^ ((srow ^ (srow >> 3)) & 3);
  const u16* ga = A + (size_t)(m0 + srow) * D_DIM + sch * 8;
  const u16* gb = B + (size_t)(n0 + srow) * D_DIM + sch * 8;
  for (int k0 = 0; k0 < D_DIM; k0 += 32) {
    load_lds16(ga + k0, &lA[t * 8]);
    load_lds16(ga + (size_t)64 * D_DIM + k0, &lA[2048 + t * 8]);
    load_lds16(gb + k0, &lB[t * 8]);
    load_lds16(gb + (size_t)64 * D_DIM + k0, &lB[2048 + t * 8]);
    __syncthreads();
    short8 af[4], bfr[4];
#pragma unroll
    for (int m = 0; m < 4; ++m) {
      const int R = wr * 64 + m * 16 + lo;
      af[m] = *(const short8*)&lA[R * 32 + ((g ^ ((R ^ (R >> 3)) & 3)) << 3)];
    }
#pragma unroll
    for (int n = 0; n < 4; ++n) {
      const int R = wc * 64 + n * 16 + lo;
      bfr[n] = *(const short8*)&lB[R * 32 + ((g ^ ((R ^ (R >> 3)) & 3)) << 3)];
    }
#pragma unroll
    for (int m = 0; m < 4; ++m)
#pragma unroll
      for (int n = 0; n < 4; ++n) acc[m][n] = MFMA16(af[m], bfr[n], acc[m][n]);
    __syncthreads();
  }
}

// ---------------- fused QKV GEMM: 1152 blocks, A-resident XCD chunking, plain epilogue ----------------
__global__ __launch_bounds__(256) void k_gemm_qkv(const u16* __restrict__ A,
                                                  const u16* __restrict__ Bq, const u16* __restrict__ Bk,
                                                  const u16* __restrict__ Bv,
                                                  const float* __restrict__ bq, const float* __restrict__ bk,
                                                  const float* __restrict__ bv,
                                                  u16* __restrict__ Qb, u16* __restrict__ Kb,
                                                  u16* __restrict__ Vb) {
  __shared__ u16 lA[128 * 32];
  __shared__ u16 lB[128 * 32];
  const int id = blockIdx.x;
  const int xcd = id & 7, local = id >> 3;       // 144 blocks per XCD
  const int m_idx = xcd * 3 + local / 48;        // x-chunk (1.6 MB) L2-hot per XCD
  const int n_idx = local % 48;
  const int m0 = m_idx * 128;
  const int seg = n_idx >> 4, n0 = (n_idx & 15) * 128;
  const u16* B = seg == 0 ? Bq : seg == 1 ? Bk : Bv;
  const float* bias = seg == 0 ? bq : seg == 1 ? bk : bv;
  u16* D = seg == 0 ? Qb : seg == 1 ? Kb : Vb;
  const int t = threadIdx.x;
  const int lane = t & 63, w = t >> 6, lo = lane & 15, g = lane >> 4;
  const int wr = w >> 1, wc = w & 1;
  const f32x4 zero4 = {0.f, 0.f, 0.f, 0.f};
  f32x4 acc[4][4];
#pragma unroll
  for (int m = 0; m < 4; ++m)
#pragma unroll
    for (int n = 0; n < 4; ++n) acc[m][n] = zero4;
  gemm_body(A, B, m0, n0, t, acc, lA, lB);
#pragma unroll
  for (int m = 0; m < 4; ++m) {
    const int row = m0 + wr * 64 + m * 16 + 4 * g;
#pragma unroll
    for (int n = 0; n < 4; ++n) {
      const int col = n0 + wc * 64 + n * 16 + lo;
      const float bb = bias[col];
#pragma unroll
      for (int r = 0; r < 4; ++r)
        D[(size_t)(row + r) * 2048 + col] = f2bf(acc[m][n][r] + bb);
    }
  }
}

// ---------------- WO GEMM: 384 blocks, A-resident XCD chunking, fp32 out ----------------
__global__ __launch_bounds__(256) void k_gemm_wo(const u16* __restrict__ A,
                                                 const u16* __restrict__ B,
                                                 const float* __restrict__ bias,
                                                 float* __restrict__ C) {
  __shared__ u16 lA[128 * 32];
  __shared__ u16 lB[128 * 32];
  const int id = blockIdx.x;
  const int xcd = id & 7, local = id >> 3;   // 48 per XCD
  const int m_idx = xcd * 3 + local / 16;
  const int n_idx = local % 16;
  const int m0 = m_idx * 128, n0 = n_idx * 128;
  const int t = threadIdx.x;
  const int lane = t & 63, w = t >> 6, lo = lane & 15, g = lane >> 4;
  const int wr = w >> 1, wc = w & 1;
  const f32x4 zero4 = {0.f, 0.f, 0.f, 0.f};
  f32x4 acc[4][4];
#pragma unroll
  for (int m = 0; m < 4; ++m)
#pragma unroll
    for (int n = 0; n < 4; ++n) acc[m][n] = zero4;
  gemm_body(A, B, m0, n0, t, acc, lA, lB);
#pragma unroll
  for (int m = 0; m < 4; ++m) {
    const int row = m0 + wr * 64 + m * 16 + 4 * g;
#pragma unroll
    for (int n = 0; n < 4; ++n) {
      const int col = n0 + wc * 64 + n * 16 + lo;
      const float bb = bias[col];
#pragma unroll
      for (int r = 0; r < 4; ++r)
        C[(size_t)(row + r) * 2048 + col] = acc[m][n][r] + bb;
    }
  }
}

// ---------------- fused RMSNorm + RoPE for Q and K, one launch (grid (S,2)) ----------------
__global__ __launch_bounds__(256) void k_rms_rope2(const u16* __restrict__ Q0, const u16* __restrict__ K0,
                                                   const float* __restrict__ gq, const float* __restrict__ gk,
                                                   const float* __restrict__ cosT, const float* __restrict__ sinT,
                                                   u16* __restrict__ qo, u16* __restrict__ ko) {
  const int s = blockIdx.x, t = threadIdx.x;
  const u16* H = blockIdx.y ? K0 : Q0;
  const float* gain = blockIdx.y ? gk : gq;
  u16* out = blockIdx.y ? ko : qo;
  const short8 hv = *(const short8*)(H + (size_t)s * D_DIM + t * 8);
  float h[8];
#pragma unroll
  for (int j = 0; j < 8; ++j) h[j] = bf2f((u16)hv[j]);
  float ss = 0.f;
#pragma unroll
  for (int j = 0; j < 8; ++j) ss += h[j] * h[j];
#pragma unroll
  for (int off = 32; off > 0; off >>= 1) ss += __shfl_xor(ss, off);
  __shared__ float red[4];
  if ((t & 63) == 0) red[t >> 6] = ss;
  __syncthreads();
  ss = red[0] + red[1] + red[2] + red[3];
  const float rs = rsqrtf(ss * (1.f / D_DIM) + 1e-6f);
  const float4 g0 = *(const float4*)(gain + t * 8);
  const float4 g1 = *(const float4*)(gain + t * 8 + 4);
  float y[8];
  y[0] = h[0] * rs * g0.x; y[1] = h[1] * rs * g0.y;
  y[2] = h[2] * rs * g0.z; y[3] = h[3] * rs * g0.w;
  y[4] = h[4] * rs * g1.x; y[5] = h[5] * rs * g1.y;
  y[6] = h[6] * rs * g1.z; y[7] = h[7] * rs * g1.w;
  const int cbase = ((t * 8) & 127) >> 1;
  short8 o8;
#pragma unroll
  for (int i = 0; i < 4; ++i) {
    const float cs = cosT[s * 64 + cbase + i];
    const float sn = sinT[s * 64 + cbase + i];
    const float yr = y[2 * i] * cs - y[2 * i + 1] * sn;
    const float yi = y[2 * i] * sn + y[2 * i + 1] * cs;
    o8[2 * i] = (short)f2bf(yr);
    o8[2 * i + 1] = (short)f2bf(yi);
  }
  *(short8*)(out + (size_t)s * D_DIM + t * 8) = o8;
}

// ---------------- bf16 transpose [S][D] -> [D][S] (64x64 tiles) ----------------
__global__ __launch_bounds__(256) void k_transpose(const u16* __restrict__ in,
                                                   u16* __restrict__ out) {
  __shared__ u16 tile[64][72];
  const int s0 = blockIdx.x * 64, d0 = blockIdx.y * 64;
  const int t = threadIdx.x;
  const int r = t >> 3, c8 = (t & 7) * 8;
#pragma unroll
  for (int p = 0; p < 2; ++p) {
    short8 v = *(const short8*)&in[(size_t)(s0 + r + p * 32) * D_DIM + d0 + c8];
#pragma unroll
    for (int j = 0; j < 8; ++j) tile[r + p * 32][c8 + j] = (u16)v[j];
  }
  __syncthreads();
#pragma unroll
  for (int p = 0; p < 2; ++p) {
    const int dr = r + p * 32;
    short8 o;
#pragma unroll
    for (int j = 0; j < 8; ++j) o[j] = (short)tile[c8 + j][dr];
    *(short8*)&out[(size_t)(d0 + dr) * S_LEN + s0 + c8] = o;
  }
}

// ---------------- banded flash attention: QBLK=128, double-buffered staging ----------------
__global__ __launch_bounds__(256, 3) void k_attn5(const u16* __restrict__ Q,
                                                  const u16* __restrict__ Kmat,
                                                  const u16* __restrict__ Vt,
                                                  u16* __restrict__ Oa,
                                                  u16* __restrict__ Ob,
                                                  float* __restrict__ lbuf) {
  const int qt = blockIdx.x, h = blockIdx.y, z = blockIdx.z;
  const int t = threadIdx.x, w = t >> 6, lane = t & 63, lo = lane & 15, g = lane >> 4;
  const int q0 = qt * 128;
  const int wrow = q0 + w * 32;
  const size_t hoff = (size_t)h * 128;

  __shared__ u16 lK[2][32 * 128];
  __shared__ u16 lV[2][128 * 32];
  __shared__ u16 ldsp[4][32][40];

  short8 qf[2][4];
#pragma unroll
  for (int m = 0; m < 2; ++m) {
    const u16* qp = Q + (size_t)(wrow + m * 16 + lo) * D_DIM + hoff + g * 8;
#pragma unroll
    for (int c = 0; c < 4; ++c) qf[m][c] = *(const short8*)(qp + c * 32);
  }

  const f32x4 zero4 = {0.f, 0.f, 0.f, 0.f};
  f32x4 oacc[2][8];
#pragma unroll
  for (int m = 0; m < 2; ++m)
#pragma unroll
    for (int ct = 0; ct < 8; ++ct) oacc[m][ct] = zero4;
  float lrun[2][4] = {{0.f, 0.f, 0.f, 0.f}, {0.f, 0.f, 0.f, 0.f}};

  int jlo = q0 - WIN; if (jlo < 0) jlo = 0;
  int jhi = q0 + 127 + WIN + 1; if (jhi > S_LEN) jhi = S_LEN;
  const int NT = (jhi - jlo) >> 5;
  const int it0 = z * (NT >> 1), it1 = it0 + (NT >> 1);

  const int krow = t >> 4,          kch  = (t & 15) ^ (krow & 7);
  const int krow1 = (t + 256) >> 4, kch1 = (t & 15) ^ (krow1 & 7);
  const int vrow = t >> 2,          vch  = (t & 3) ^ ((vrow >> 1) & 3);
  const int vrow1 = (t + 256) >> 2, vch1 = (t & 3) ^ ((vrow1 >> 1) & 3);

#define STAGE5(buf, jj)                                                                              \
  do {                                                                                               \
    load_lds16(Kmat + (size_t)((jj) + krow) * D_DIM + hoff + (kch << 3), &lK[buf][t * 8]);           \
    load_lds16(Kmat + (size_t)((jj) + krow1) * D_DIM + hoff + (kch1 << 3), &lK[buf][(t + 256) * 8]); \
    load_lds16(Vt + (size_t)(hoff + vrow) * S_LEN + (jj) + (vch << 3), &lV[buf][t * 8]);             \
    load_lds16(Vt + (size_t)(hoff + vrow1) * S_LEN + (jj) + (vch1 << 3), &lV[buf][(t + 256) * 8]);   \
  } while (0)

  STAGE5(0, jlo + (it0 << 5));
  __syncthreads();
  int cur = 0;
  for (int it = it0; it < it1; ++it) {
    const int j0 = jlo + (it << 5);
    if (it + 1 < it1) STAGE5(cur ^ 1, j0 + 32);

    f32x4 sc[2][2];
    sc[0][0] = zero4; sc[0][1] = zero4; sc[1][0] = zero4; sc[1][1] = zero4;
#pragma unroll
    for (int half = 0; half < 2; ++half) {
#pragma unroll
      for (int c = 0; c < 4; ++c) {
        const short8 kf = *(const short8*)
            &lK[cur][(half * 16 + lo) * 128 + (((g + 4 * c) ^ (lo & 7)) << 3)];
        sc[0][half] = MFMA16(qf[0][c], kf, sc[0][half]);
        sc[1][half] = MFMA16(qf[1][c], kf, sc[1][half]);
      }
    }

    const int dq = j0 - q0;
    const bool interior = (dq >= -640) && (dq <= 736);
#pragma unroll
    for (int m = 0; m < 2; ++m) {
#pragma unroll
      for (int r = 0; r < 4; ++r) {
        float a0 = fmaf(sc[m][0][r], INV_SQRT_HD, -M_SHIFT);
        float a1 = fmaf(sc[m][1][r], INV_SQRT_HD, -M_SHIFT);
        if (!interior) {
          const int dk = j0 + lo - (wrow + m * 16 + 4 * g + r);
          if (dk < -WIN || dk > WIN) a0 = -3e38f;
          if (dk + 16 < -WIN || dk + 16 > WIN) a1 = -3e38f;
        }
        const float p0 = __expf(a0);
        const float p1 = __expf(a1);
        lrun[m][r] += p0 + p1;
        ldsp[w][m * 16 + 4 * g + r][lo] = f2bf(p0);
        ldsp[w][m * 16 + 4 * g + r][16 + lo] = f2bf(p1);
      }
    }

    const short8 pf0 = *(const short8*)&ldsp[w][lo][g * 8];
    const short8 pf1 = *(const short8*)&ldsp[w][16 + lo][g * 8];
#pragma unroll
    for (int ct = 0; ct < 8; ++ct) {
      const short8 vf = *(const short8*)
          &lV[cur][(ct * 16 + lo) * 32 + ((g ^ ((lo >> 1) & 3)) << 3)];
      oacc[0][ct] = MFMA16(pf0, vf, oacc[0][ct]);
      oacc[1][ct] = MFMA16(pf1, vf, oacc[1][ct]);
    }
    __syncthreads();
    cur ^= 1;
  }
#undef STAGE5

#pragma unroll
  for (int off = 8; off > 0; off >>= 1)
#pragma unroll
    for (int m = 0; m < 2; ++m)
#pragma unroll
      for (int r = 0; r < 4; ++r) lrun[m][r] += __shfl_xor(lrun[m][r], off);

  u16* Op = z ? Ob : Oa;
#pragma unroll
  for (int m = 0; m < 2; ++m)
#pragma unroll
    for (int r = 0; r < 4; ++r) {
      const int row = wrow + m * 16 + 4 * g + r;
#pragma unroll
      for (int ct = 0; ct < 8; ++ct)
        Op[(size_t)row * D_DIM + hoff + ct * 16 + lo] = f2bf(oacc[m][ct][r]);
      if (lo == 0) lbuf[(size_t)z * S_LEN * 16 + (size_t)row * 16 + h] = lrun[m][r];
    }
}

// ---------------- combine: out = (Oa + Ob) / (la + lb), bf16 ----------------
__global__ __launch_bounds__(256) void k_combine(const u16* __restrict__ Oa,
                                                 const u16* __restrict__ Ob,
                                                 const float* __restrict__ lbuf,
                                                 u16* __restrict__ out) {
  const int i = blockIdx.x * 256 + threadIdx.x;
  const int s = i >> 8, d8 = (i & 255) * 8, h = d8 >> 7;
  const float la = lbuf[(size_t)s * 16 + h];
  const float lb = lbuf[(size_t)S_LEN * 16 + (size_t)s * 16 + h];
  const float inv = 1.f / (la + lb);
  const size_t base = (size_t)s * D_DIM + d8;
  const short8 a = *(const short8*)(Oa + base);
  const short8 b = *(const short8*)(Ob + base);
  short8 o;
#pragma unroll
  for (int j = 0; j < 8; ++j)
    o[j] = (short)f2bf((bf2f((u16)a[j]) + bf2f((u16)b[j])) * inv);
  *(short8*)(out + base) = o;
}

extern "C" void kernel_launch(void* const* d_in, const int* in_sizes, int n_in,
                              void* d_out, int out_size, void* d_ws, size_t ws_size,
                              hipStream_t stream) {
  const float* x    = (const float*)d_in[0];
  const float* wq   = (const float*)d_in[1];
  const float* bq   = (const float*)d_in[2];
  const float* wk   = (const float*)d_in[3];
  const float* bk   = (const float*)d_in[4];
  const float* wv   = (const float*)d_in[5];
  const float* bv   = (const float*)d_in[6];
  const float* wo   = (const float*)d_in[7];
  const float* bo   = (const float*)d_in[8];
  const float* gq   = (const float*)d_in[9];
  const float* gk   = (const float*)d_in[10];
  const float* cosT = (const float*)d_in[11];
  const float* sinT = (const float*)d_in[12];

  char* ws = (char*)d_ws;
  const size_t WB = (size_t)D_DIM * D_DIM * 2;  // 8.4 MB
  const size_t XB = (size_t)S_LEN * D_DIM * 2;  // 12.6 MB
  u16*   wq_bf = (u16*)(ws);
  u16*   wk_bf = (u16*)(ws + WB);
  u16*   wv_bf = (u16*)(ws + 2 * WB);
  u16*   wo_bf = (u16*)(ws + 3 * WB);
  u16*   x_bf  = (u16*)(ws + 4 * WB);
  u16*   Q0b   = (u16*)(ws + 4 * WB + XB);
  u16*   K0b   = (u16*)(ws + 4 * WB + 2 * XB);
  u16*   V0b   = (u16*)(ws + 4 * WB + 3 * XB);
  float* lbuf  = (float*)(ws + 4 * WB + 4 * XB);  // 2*S*16 fp32
  // stream-ordered reuse:
  u16* q_bf = x_bf;          // x_bf dead after QKV GEMM
  u16* k_bf = wq_bf;         // wq/wk/wv bf16 dead after QKV GEMM
  u16* vT   = Q0b;           // Q0b dead after rms_rope2
  u16* Ob   = K0b;           // K0b dead after rms_rope2
  u16* Oa   = (u16*)d_out;   // scratch; overwritten by final GEMM
  u16* attn = V0b;           // V0b dead after k_transpose

  const int nw4 = (D_DIM * D_DIM) / 4;
  const int nx4 = (S_LEN * D_DIM) / 4;
  k_cvt_all<<<(nx4 + 4 * nw4) / 256, 256, 0, stream>>>(
      x, wq, wk, wv, wo, x_bf, wq_bf, wk_bf, wv_bf, wo_bf, nx4, nw4);

  k_gemm_qkv<<<1152, 256, 0, stream>>>(x_bf, wq_bf, wk_bf, wv_bf, bq, bk, bv, Q0b, K0b, V0b);

  k_rms_rope2<<<dim3(S_LEN, 2), 256, 0, stream>>>(Q0b, K0b, gq, gk, cosT, sinT, q_bf, k_bf);
  k_transpose<<<dim3(S_LEN / 64, D_DIM / 64), 256, 0, stream>>>(V0b, vT);

  k_attn5<<<dim3(S_LEN / 128, 16, 2), 256, 0, stream>>>(q_bf, k_bf, vT, Oa, Ob, lbuf);
  k_combine<<<(S_LEN * D_DIM / 8) / 256, 256, 0, stream>>>(Oa, Ob, lbuf, attn);

  k_gemm_wo<<<384, 256, 0, stream>>>(attn, wo_bf, bo, (float*)d_out);
}

// Round 14
// 228.845 us; speedup vs baseline: 1.3164x; 1.1186x over previous
//
#include <hip/hip_runtime.h>
#include <stdint.h>

typedef unsigned short u16;
typedef __attribute__((ext_vector_type(8))) short short8;
typedef __attribute__((ext_vector_type(4))) float f32x4;

#define S_LEN 3072
#define D_DIM 2048
#define WIN 768
#define INV_SQRT_HD 0.08838834764831845f
#define M_SHIFT 12.0f

__device__ __forceinline__ u16 f2bf(float x) {
  union { float f; uint32_t u; } v; v.f = x;
  uint32_t r = v.u + 0x7FFFu + ((v.u >> 16) & 1u);
  return (u16)(r >> 16);
}
__device__ __forceinline__ float bf2f(u16 x) {
  union { uint32_t u; float f; } v; v.u = ((uint32_t)x) << 16;
  return v.f;
}

__device__ __forceinline__ void load_lds16(const void* g, void* l) {
  __builtin_amdgcn_global_load_lds(
      (const __attribute__((address_space(1))) void*)g,
      (__attribute__((address_space(3))) void*)l, 16, 0, 0);
}

#define MFMA16(a, b, c) __builtin_amdgcn_mfma_f32_16x16x32_bf16((a), (b), (c), 0, 0, 0)

// ------- fused fp32 -> bf16 convert: x + 4 weights + packed QKV bias, one launch -------
__global__ __launch_bounds__(256) void k_cvt_all(const float* __restrict__ x,
                                                 const float* __restrict__ w0, const float* __restrict__ w1,
                                                 const float* __restrict__ w2, const float* __restrict__ w3,
                                                 const float* __restrict__ bq, const float* __restrict__ bk,
                                                 const float* __restrict__ bv,
                                                 u16* __restrict__ xo,
                                                 u16* __restrict__ o0, u16* __restrict__ o1,
                                                 u16* __restrict__ o2, u16* __restrict__ o3,
                                                 float* __restrict__ bias_all,
                                                 int n4x, int n4w) {
  int i = blockIdx.x * 256 + threadIdx.x;
  if (i < n4x + 4 * n4w) {
    const float* in;
    u16* out;
    int off;
    if (i < n4x) {
      in = x; out = xo; off = i;
    } else {
      int j = i - n4x;
      int seg = j / n4w;
      off = j - seg * n4w;
      in = seg == 0 ? w0 : seg == 1 ? w1 : seg == 2 ? w2 : w3;
      out = seg == 0 ? o0 : seg == 1 ? o1 : seg == 2 ? o2 : o3;
    }
    float4 v = ((const float4*)in)[off];
    ushort4 o;
    o.x = f2bf(v.x); o.y = f2bf(v.y); o.z = f2bf(v.z); o.w = f2bf(v.w);
    ((ushort4*)out)[off] = o;
  } else {
    int j = i - n4x - 4 * n4w;             // 0..1535  (6144 floats / 4)
    int seg = j >> 9, off = j & 511;       // 512 quads per bias
    const float* in = seg == 0 ? bq : seg == 1 ? bk : bv;
    ((float4*)bias_all)[j] = ((const float4*)in)[off];
  }
}

// ---------------- QKV GEMM: 128x192 tile, acc 4x6, BK=32, 768 blocks (zero-tail) ----------------
// B is the CONTIGUOUS [6144][2048] bf16 block wq|wk|wv; outputs contiguous Q|K|V.
// A-resident XCD chunking: xcd owns 3 M-rows x 32 N-tiles.
__global__ __launch_bounds__(256, 3) void k_gemm_qkv(const u16* __restrict__ A,
                                                     const u16* __restrict__ Ball,
                                                     const float* __restrict__ bias_all,
                                                     u16* __restrict__ QKV) {
  __shared__ u16 lA[128 * 32];
  __shared__ u16 lB[192 * 32];
  const int id = blockIdx.x;
  const int xcd = id & 7, local = id >> 3;   // 96 per XCD
  const int m_idx = xcd * 3 + local / 32;    // x-chunk (1.6 MB) L2-hot per XCD
  const int n_idx = local % 32;
  const int m0 = m_idx * 128;
  const int n0g = n_idx * 192;               // global col in [0, 6144)
  const int t = threadIdx.x;
  const int lane = t & 63, w = t >> 6, lo = lane & 15, g = lane >> 4;
  const int wr = w >> 1, wc = w & 1;

  const int srow = t >> 2;
  const int sch = (t & 3) ^ ((srow ^ (srow >> 3)) & 3);  // swizzle invariant under row+=64/128
  const u16* ga = A + (size_t)(m0 + srow) * D_DIM + sch * 8;
  const u16* gb = Ball + (size_t)(n0g + srow) * D_DIM + sch * 8;

  const f32x4 zero4 = {0.f, 0.f, 0.f, 0.f};
  f32x4 acc[4][6];
#pragma unroll
  for (int m = 0; m < 4; ++m)
#pragma unroll
    for (int n = 0; n < 6; ++n) acc[m][n] = zero4;

  for (int k0 = 0; k0 < D_DIM; k0 += 32) {
    load_lds16(ga + k0, &lA[t * 8]);
    load_lds16(ga + (size_t)64 * D_DIM + k0, &lA[2048 + t * 8]);
    load_lds16(gb + k0, &lB[t * 8]);
    load_lds16(gb + (size_t)64 * D_DIM + k0, &lB[2048 + t * 8]);
    load_lds16(gb + (size_t)128 * D_DIM + k0, &lB[4096 + t * 8]);
    __syncthreads();
    short8 af[4], bfr[6];
#pragma unroll
    for (int m = 0; m < 4; ++m) {
      const int R = wr * 64 + m * 16 + lo;
      af[m] = *(const short8*)&lA[R * 32 + ((g ^ ((R ^ (R >> 3)) & 3)) << 3)];
    }
#pragma unroll
    for (int n = 0; n < 6; ++n) {
      const int R = wc * 96 + n * 16 + lo;
      bfr[n] = *(const short8*)&lB[R * 32 + ((g ^ ((R ^ (R >> 3)) & 3)) << 3)];
    }
#pragma unroll
    for (int m = 0; m < 4; ++m)
#pragma unroll
      for (int n = 0; n < 6; ++n) acc[m][n] = MFMA16(af[m], bfr[n], acc[m][n]);
    __syncthreads();
  }

#pragma unroll
  for (int m = 0; m < 4; ++m) {
    const int row = m0 + wr * 64 + m * 16 + 4 * g;
#pragma unroll
    for (int n = 0; n < 6; ++n) {
      const int col_g = n0g + wc * 96 + n * 16 + lo;
      const int seg_c = col_g >> 11, c = col_g & 2047;
      u16* D = QKV + (size_t)seg_c * S_LEN * D_DIM;
      const float bb = bias_all[col_g];
#pragma unroll
      for (int r = 0; r < 4; ++r)
        D[(size_t)(row + r) * D_DIM + c] = f2bf(acc[m][n][r] + bb);
    }
  }
}

// ---------------- 128x128 GEMM body, BK=32 (m97 pattern) for WO ----------------
__device__ __forceinline__ void gemm_body(const u16* __restrict__ A, const u16* __restrict__ B,
                                          int m0, int n0, int t, f32x4 (*acc)[4],
                                          u16* lA, u16* lB) {
  const int lane = t & 63, w = t >> 6, lo = lane & 15, g = lane >> 4;
  const int wr = w >> 1, wc = w & 1;
  const int srow = t >> 2;
  const int sch = (t & 3) ^ ((srow ^ (srow >> 3)) & 3);
  const u16* ga = A + (size_t)(m0 + srow) * D_DIM + sch * 8;
  const u16* gb = B + (size_t)(n0 + srow) * D_DIM + sch * 8;
  for (int k0 = 0; k0 < D_DIM; k0 += 32) {
    load_lds16(ga + k0, &lA[t * 8]);
    load_lds16(ga + (size_t)64 * D_DIM + k0, &lA[2048 + t * 8]);
    load_lds16(gb + k0, &lB[t * 8]);
    load_lds16(gb + (size_t)64 * D_DIM + k0, &lB[2048 + t * 8]);
    __syncthreads();
    short8 af[4], bfr[4];
#pragma unroll
    for (int m = 0; m < 4; ++m) {
      const int R = wr * 64 + m * 16 + lo;
      af[m] = *(const short8*)&lA[R * 32 + ((g ^ ((R ^ (R >> 3)) & 3)) << 3)];
    }
#pragma unroll
    for (int n = 0; n < 4; ++n) {
      const int R = wc * 64 + n * 16 + lo;
      bfr[n] = *(const short8*)&lB[R * 32 + ((g ^ ((R ^ (R >> 3)) & 3)) << 3)];
    }
#pragma unroll
    for (int m = 0; m < 4; ++m)
#pragma unroll
      for (int n = 0; n < 4; ++n) acc[m][n] = MFMA16(af[m], bfr[n], acc[m][n]);
    __syncthreads();
  }
}

// ---------------- WO GEMM: 384 blocks, A-resident XCD chunking, fp32 out ----------------
__global__ __launch_bounds__(256) void k_gemm_wo(const u16* __restrict__ A,
                                                 const u16* __restrict__ B,
                                                 const float* __restrict__ bias,
                                                 float* __restrict__ C) {
  __shared__ u16 lA[128 * 32];
  __shared__ u16 lB[128 * 32];
  const int id = blockIdx.x;
  const int xcd = id & 7, local = id >> 3;   // 48 per XCD
  const int m_idx = xcd * 3 + local / 16;
  const int n_idx = local % 16;
  const int m0 = m_idx * 128, n0 = n_idx * 128;
  const int t = threadIdx.x;
  const int lane = t & 63, w = t >> 6, lo = lane & 15, g = lane >> 4;
  const int wr = w >> 1, wc = w & 1;
  const f32x4 zero4 = {0.f, 0.f, 0.f, 0.f};
  f32x4 acc[4][4];
#pragma unroll
  for (int m = 0; m < 4; ++m)
#pragma unroll
    for (int n = 0; n < 4; ++n) acc[m][n] = zero4;
  gemm_body(A, B, m0, n0, t, acc, lA, lB);
#pragma unroll
  for (int m = 0; m < 4; ++m) {
    const int row = m0 + wr * 64 + m * 16 + 4 * g;
#pragma unroll
    for (int n = 0; n < 4; ++n) {
      const int col = n0 + wc * 64 + n * 16 + lo;
      const float bb = bias[col];
#pragma unroll
      for (int r = 0; r < 4; ++r)
        C[(size_t)(row + r) * 2048 + col] = acc[m][n][r] + bb;
    }
  }
}

// ---------------- fused RMSNorm + RoPE for Q and K, one launch (grid (S,2)) ----------------
__global__ __launch_bounds__(256) void k_rms_rope2(const u16* __restrict__ Q0, const u16* __restrict__ K0,
                                                   const float* __restrict__ gq, const float* __restrict__ gk,
                                                   const float* __restrict__ cosT, const float* __restrict__ sinT,
                                                   u16* __restrict__ qo, u16* __restrict__ ko) {
  const int s = blockIdx.x, t = threadIdx.x;
  const u16* H = blockIdx.y ? K0 : Q0;
  const float* gain = blockIdx.y ? gk : gq;
  u16* out = blockIdx.y ? ko : qo;
  const short8 hv = *(const short8*)(H + (size_t)s * D_DIM + t * 8);
  float h[8];
#pragma unroll
  for (int j = 0; j < 8; ++j) h[j] = bf2f((u16)hv[j]);
  float ss = 0.f;
#pragma unroll
  for (int j = 0; j < 8; ++j) ss += h[j] * h[j];
#pragma unroll
  for (int off = 32; off > 0; off >>= 1) ss += __shfl_xor(ss, off);
  __shared__ float red[4];
  if ((t & 63) == 0) red[t >> 6] = ss;
  __syncthreads();
  ss = red[0] + red[1] + red[2] + red[3];
  const float rs = rsqrtf(ss * (1.f / D_DIM) + 1e-6f);
  const float4 g0 = *(const float4*)(gain + t * 8);
  const float4 g1 = *(const float4*)(gain + t * 8 + 4);
  float y[8];
  y[0] = h[0] * rs * g0.x; y[1] = h[1] * rs * g0.y;
  y[2] = h[2] * rs * g0.z; y[3] = h[3] * rs * g0.w;
  y[4] = h[4] * rs * g1.x; y[5] = h[5] * rs * g1.y;
  y[6] = h[6] * rs * g1.z; y[7] = h[7] * rs * g1.w;
  const int cbase = ((t * 8) & 127) >> 1;
  short8 o8;
#pragma unroll
  for (int i = 0; i < 4; ++i) {
    const float cs = cosT[s * 64 + cbase + i];
    const float sn = sinT[s * 64 + cbase + i];
    const float yr = y[2 * i] * cs - y[2 * i + 1] * sn;
    const float yi = y[2 * i] * sn + y[2 * i + 1] * cs;
    o8[2 * i] = (short)f2bf(yr);
    o8[2 * i + 1] = (short)f2bf(yi);
  }
  *(short8*)(out + (size_t)s * D_DIM + t * 8) = o8;
}

// ---------------- bf16 transpose [S][D] -> [D][S] (64x64 tiles) ----------------
__global__ __launch_bounds__(256) void k_transpose(const u16* __restrict__ in,
                                                   u16* __restrict__ out) {
  __shared__ u16 tile[64][72];
  const int s0 = blockIdx.x * 64, d0 = blockIdx.y * 64;
  const int t = threadIdx.x;
  const int r = t >> 3, c8 = (t & 7) * 8;
#pragma unroll
  for (int p = 0; p < 2; ++p) {
    short8 v = *(const short8*)&in[(size_t)(s0 + r + p * 32) * D_DIM + d0 + c8];
#pragma unroll
    for (int j = 0; j < 8; ++j) tile[r + p * 32][c8 + j] = (u16)v[j];
  }
  __syncthreads();
#pragma unroll
  for (int p = 0; p < 2; ++p) {
    const int dr = r + p * 32;
    short8 o;
#pragma unroll
    for (int j = 0; j < 8; ++j) o[j] = (short)tile[c8 + j][dr];
    *(short8*)&out[(size_t)(d0 + dr) * S_LEN + s0 + c8] = o;
  }
}

// ---------------- banded flash attention: QBLK=128, double-buffered staging ----------------
__global__ __launch_bounds__(256, 3) void k_attn5(const u16* __restrict__ Q,
                                                  const u16* __restrict__ Kmat,
                                                  const u16* __restrict__ Vt,
                                                  u16* __restrict__ Oa,
                                                  u16* __restrict__ Ob,
                                                  float* __restrict__ lbuf) {
  const int qt = blockIdx.x, h = blockIdx.y, z = blockIdx.z;
  const int t = threadIdx.x, w = t >> 6, lane = t & 63, lo = lane & 15, g = lane >> 4;
  const int q0 = qt * 128;
  const int wrow = q0 + w * 32;
  const size_t hoff = (size_t)h * 128;

  __shared__ u16 lK[2][32 * 128];
  __shared__ u16 lV[2][128 * 32];
  __shared__ u16 ldsp[4][32][40];

  short8 qf[2][4];
#pragma unroll
  for (int m = 0; m < 2; ++m) {
    const u16* qp = Q + (size_t)(wrow + m * 16 + lo) * D_DIM + hoff + g * 8;
#pragma unroll
    for (int c = 0; c < 4; ++c) qf[m][c] = *(const short8*)(qp + c * 32);
  }

  const f32x4 zero4 = {0.f, 0.f, 0.f, 0.f};
  f32x4 oacc[2][8];
#pragma unroll
  for (int m = 0; m < 2; ++m)
#pragma unroll
    for (int ct = 0; ct < 8; ++ct) oacc[m][ct] = zero4;
  float lrun[2][4] = {{0.f, 0.f, 0.f, 0.f}, {0.f, 0.f, 0.f, 0.f}};

  int jlo = q0 - WIN; if (jlo < 0) jlo = 0;
  int jhi = q0 + 127 + WIN + 1; if (jhi > S_LEN) jhi = S_LEN;
  const int NT = (jhi - jlo) >> 5;
  const int it0 = z * (NT >> 1), it1 = it0 + (NT >> 1);

  const int krow = t >> 4,          kch  = (t & 15) ^ (krow & 7);
  const int krow1 = (t + 256) >> 4, kch1 = (t & 15) ^ (krow1 & 7);
  const int vrow = t >> 2,          vch  = (t & 3) ^ ((vrow >> 1) & 3);
  const int vrow1 = (t + 256) >> 2, vch1 = (t & 3) ^ ((vrow1 >> 1) & 3);

#define STAGE5(buf, jj)                                                                              \
  do {                                                                                               \
    load_lds16(Kmat + (size_t)((jj) + krow) * D_DIM + hoff + (kch << 3), &lK[buf][t * 8]);           \
    load_lds16(Kmat + (size_t)((jj) + krow1) * D_DIM + hoff + (kch1 << 3), &lK[buf][(t + 256) * 8]); \
    load_lds16(Vt + (size_t)(hoff + vrow) * S_LEN + (jj) + (vch << 3), &lV[buf][t * 8]);             \
    load_lds16(Vt + (size_t)(hoff + vrow1) * S_LEN + (jj) + (vch1 << 3), &lV[buf][(t + 256) * 8]);   \
  } while (0)

  STAGE5(0, jlo + (it0 << 5));
  __syncthreads();
  int cur = 0;
  for (int it = it0; it < it1; ++it) {
    const int j0 = jlo + (it << 5);
    if (it + 1 < it1) STAGE5(cur ^ 1, j0 + 32);

    f32x4 sc[2][2];
    sc[0][0] = zero4; sc[0][1] = zero4; sc[1][0] = zero4; sc[1][1] = zero4;
#pragma unroll
    for (int half = 0; half < 2; ++half) {
#pragma unroll
      for (int c = 0; c < 4; ++c) {
        const short8 kf = *(const short8*)
            &lK[cur][(half * 16 + lo) * 128 + (((g + 4 * c) ^ (lo & 7)) << 3)];
        sc[0][half] = MFMA16(qf[0][c], kf, sc[0][half]);
        sc[1][half] = MFMA16(qf[1][c], kf, sc[1][half]);
      }
    }

    const int dq = j0 - q0;
    const bool interior = (dq >= -640) && (dq <= 736);
#pragma unroll
    for (int m = 0; m < 2; ++m) {
#pragma unroll
      for (int r = 0; r < 4; ++r) {
        float a0 = fmaf(sc[m][0][r], INV_SQRT_HD, -M_SHIFT);
        float a1 = fmaf(sc[m][1][r], INV_SQRT_HD, -M_SHIFT);
        if (!interior) {
          const int dk = j0 + lo - (wrow + m * 16 + 4 * g + r);
          if (dk < -WIN || dk > WIN) a0 = -3e38f;
          if (dk + 16 < -WIN || dk + 16 > WIN) a1 = -3e38f;
        }
        const float p0 = __expf(a0);
        const float p1 = __expf(a1);
        lrun[m][r] += p0 + p1;
        ldsp[w][m * 16 + 4 * g + r][lo] = f2bf(p0);
        ldsp[w][m * 16 + 4 * g + r][16 + lo] = f2bf(p1);
      }
    }

    const short8 pf0 = *(const short8*)&ldsp[w][lo][g * 8];
    const short8 pf1 = *(const short8*)&ldsp[w][16 + lo][g * 8];
#pragma unroll
    for (int ct = 0; ct < 8; ++ct) {
      const short8 vf = *(const short8*)
          &lV[cur][(ct * 16 + lo) * 32 + ((g ^ ((lo >> 1) & 3)) << 3)];
      oacc[0][ct] = MFMA16(pf0, vf, oacc[0][ct]);
      oacc[1][ct] = MFMA16(pf1, vf, oacc[1][ct]);
    }
    __syncthreads();
    cur ^= 1;
  }
#undef STAGE5

#pragma unroll
  for (int off = 8; off > 0; off >>= 1)
#pragma unroll
    for (int m = 0; m < 2; ++m)
#pragma unroll
      for (int r = 0; r < 4; ++r) lrun[m][r] += __shfl_xor(lrun[m][r], off);

  u16* Op = z ? Ob : Oa;
#pragma unroll
  for (int m = 0; m < 2; ++m)
#pragma unroll
    for (int r = 0; r < 4; ++r) {
      const int row = wrow + m * 16 + 4 * g + r;
#pragma unroll
      for (int ct = 0; ct < 8; ++ct)
        Op[(size_t)row * D_DIM + hoff + ct * 16 + lo] = f2bf(oacc[m][ct][r]);
      if (lo == 0) lbuf[(size_t)z * S_LEN * 16 + (size_t)row * 16 + h] = lrun[m][r];
    }
}

// ---------------- combine: out = (Oa + Ob) / (la + lb), bf16 ----------------
__global__ __launch_bounds__(256) void k_combine(const u16* __restrict__ Oa,
                                                 const u16* __restrict__ Ob,
                                                 const float* __restrict__ lbuf,
                                                 u16* __restrict__ out) {
  const int i = blockIdx.x * 256 + threadIdx.x;
  const int s = i >> 8, d8 = (i & 255) * 8, h = d8 >> 7;
  const float la = lbuf[(size_t)s * 16 + h];
  const float lb = lbuf[(size_t)S_LEN * 16 + (size_t)s * 16 + h];
  const float inv = 1.f / (la + lb);
  const size_t base = (size_t)s * D_DIM + d8;
  const short8 a = *(const short8*)(Oa + base);
  const short8 b = *(const short8*)(Ob + base);
  short8 o;
#pragma unroll
  for (int j = 0; j < 8; ++j)
    o[j] = (short)f2bf((bf2f((u16)a[j]) + bf2f((u16)b[j])) * inv);
  *(short8*)(out + base) = o;
}

extern "C" void kernel_launch(void* const* d_in, const int* in_sizes, int n_in,
                              void* d_out, int out_size, void* d_ws, size_t ws_size,
                              hipStream_t stream) {
  const float* x    = (const float*)d_in[0];
  const float* wq   = (const float*)d_in[1];
  const float* bq   = (const float*)d_in[2];
  const float* wk   = (const float*)d_in[3];
  const float* bk   = (const float*)d_in[4];
  const float* wv   = (const float*)d_in[5];
  const float* bv   = (const float*)d_in[6];
  const float* wo   = (const float*)d_in[7];
  const float* bo   = (const float*)d_in[8];
  const float* gq   = (const float*)d_in[9];
  const float* gk   = (const float*)d_in[10];
  const float* cosT = (const float*)d_in[11];
  const float* sinT = (const float*)d_in[12];

  char* ws = (char*)d_ws;
  const size_t WB = (size_t)D_DIM * D_DIM * 2;  // 8.4 MB
  const size_t XB = (size_t)S_LEN * D_DIM * 2;  // 12.6 MB
  u16*   wq_bf = (u16*)(ws);                     // wq|wk|wv contiguous = B[6144][2048]
  u16*   wk_bf = (u16*)(ws + WB);
  u16*   wv_bf = (u16*)(ws + 2 * WB);
  u16*   wo_bf = (u16*)(ws + 3 * WB);
  u16*   x_bf  = (u16*)(ws + 4 * WB);
  u16*   Q0b   = (u16*)(ws + 4 * WB + XB);       // Q|K|V contiguous outputs
  u16*   K0b   = (u16*)(ws + 4 * WB + 2 * XB);
  u16*   V0b   = (u16*)(ws + 4 * WB + 3 * XB);
  float* lbuf  = (float*)(ws + 4 * WB + 4 * XB);              // 2*S*16 fp32
  float* bias_all = (float*)(ws + 4 * WB + 4 * XB + 512 * 1024);  // 6144 fp32
  // stream-ordered reuse:
  u16* q_bf = x_bf;          // x_bf dead after QKV GEMM
  u16* k_bf = wq_bf;         // wq/wk/wv bf16 dead after QKV GEMM
  u16* vT   = Q0b;           // Q0b dead after rms_rope2
  u16* Ob   = K0b;           // K0b dead after rms_rope2
  u16* Oa   = (u16*)d_out;   // scratch; overwritten by final GEMM
  u16* attn = V0b;           // V0b dead after k_transpose

  const int nw4 = (D_DIM * D_DIM) / 4;
  const int nx4 = (S_LEN * D_DIM) / 4;
  const int ncvt = nx4 + 4 * nw4 + 6144 / 4;
  k_cvt_all<<<ncvt / 256, 256, 0, stream>>>(
      x, wq, wk, wv, wo, bq, bk, bv, x_bf, wq_bf, wk_bf, wv_bf, wo_bf, bias_all, nx4, nw4);

  k_gemm_qkv<<<768, 256, 0, stream>>>(x_bf, wq_bf, bias_all, Q0b);

  k_rms_rope2<<<dim3(S_LEN, 2), 256, 0, stream>>>(Q0b, K0b, gq, gk, cosT, sinT, q_bf, k_bf);
  k_transpose<<<dim3(S_LEN / 64, D_DIM / 64), 256, 0, stream>>>(V0b, vT);

  k_attn5<<<dim3(S_LEN / 128, 16, 2), 256, 0, stream>>>(q_bf, k_bf, vT, Oa, Ob, lbuf);
  k_combine<<<(S_LEN * D_DIM / 8) / 256, 256, 0, stream>>>(Oa, Ob, lbuf, attn);

  k_gemm_wo<<<384, 256, 0, stream>>>(attn, wo_bf, bo, (float*)d_out);
}

// Round 15
// 221.638 us; speedup vs baseline: 1.3592x; 1.0325x over previous
//
#include <hip/hip_runtime.h>
#include <stdint.h>

typedef unsigned short u16;
typedef __attribute__((ext_vector_type(8))) short short8;
typedef __attribute__((ext_vector_type(4))) float f32x4;

#define S_LEN 3072
#define D_DIM 2048
#define WIN 768
#define INV_SQRT_HD 0.08838834764831845f
#define M_SHIFT 12.0f

__device__ __forceinline__ u16 f2bf(float x) {
  union { float f; uint32_t u; } v; v.f = x;
  uint32_t r = v.u + 0x7FFFu + ((v.u >> 16) & 1u);
  return (u16)(r >> 16);
}
__device__ __forceinline__ float bf2f(u16 x) {
  union { uint32_t u; float f; } v; v.u = ((uint32_t)x) << 16;
  return v.f;
}

__device__ __forceinline__ void load_lds16(const void* g, void* l) {
  __builtin_amdgcn_global_load_lds(
      (const __attribute__((address_space(1))) void*)g,
      (__attribute__((address_space(3))) void*)l, 16, 0, 0);
}

#define MFMA16(a, b, c) __builtin_amdgcn_mfma_f32_16x16x32_bf16((a), (b), (c), 0, 0, 0)

// ------- fused fp32 -> bf16 convert: x + 4 weights + packed QKV bias, one launch -------
__global__ __launch_bounds__(256) void k_cvt_all(const float* __restrict__ x,
                                                 const float* __restrict__ w0, const float* __restrict__ w1,
                                                 const float* __restrict__ w2, const float* __restrict__ w3,
                                                 const float* __restrict__ bq, const float* __restrict__ bk,
                                                 const float* __restrict__ bv,
                                                 u16* __restrict__ xo,
                                                 u16* __restrict__ o0, u16* __restrict__ o1,
                                                 u16* __restrict__ o2, u16* __restrict__ o3,
                                                 float* __restrict__ bias_all,
                                                 int n4x, int n4w) {
  int i = blockIdx.x * 256 + threadIdx.x;
  if (i < n4x + 4 * n4w) {
    const float* in;
    u16* out;
    int off;
    if (i < n4x) {
      in = x; out = xo; off = i;
    } else {
      int j = i - n4x;
      int seg = j / n4w;
      off = j - seg * n4w;
      in = seg == 0 ? w0 : seg == 1 ? w1 : seg == 2 ? w2 : w3;
      out = seg == 0 ? o0 : seg == 1 ? o1 : seg == 2 ? o2 : o3;
    }
    float4 v = ((const float4*)in)[off];
    ushort4 o;
    o.x = f2bf(v.x); o.y = f2bf(v.y); o.z = f2bf(v.z); o.w = f2bf(v.w);
    ((ushort4*)out)[off] = o;
  } else {
    int j = i - n4x - 4 * n4w;             // 0..1535  (6144 floats / 4)
    int seg = j >> 9, off = j & 511;       // 512 quads per bias
    const float* in = seg == 0 ? bq : seg == 1 ? bk : bv;
    ((float4*)bias_all)[j] = ((const float4*)in)[off];
  }
}

// ---------------- QKV GEMM: 128x192 tile, acc 4x6, BK=32, 768 blocks (zero-tail) ----------------
__global__ __launch_bounds__(256, 3) void k_gemm_qkv(const u16* __restrict__ A,
                                                     const u16* __restrict__ Ball,
                                                     const float* __restrict__ bias_all,
                                                     u16* __restrict__ QKV) {
  __shared__ u16 lA[128 * 32];
  __shared__ u16 lB[192 * 32];
  const int id = blockIdx.x;
  const int xcd = id & 7, local = id >> 3;   // 96 per XCD
  const int m_idx = xcd * 3 + local / 32;    // x-chunk (1.6 MB) L2-hot per XCD
  const int n_idx = local % 32;
  const int m0 = m_idx * 128;
  const int n0g = n_idx * 192;               // global col in [0, 6144)
  const int t = threadIdx.x;
  const int lane = t & 63, w = t >> 6, lo = lane & 15, g = lane >> 4;
  const int wr = w >> 1, wc = w & 1;

  const int srow = t >> 2;
  const int sch = (t & 3) ^ ((srow ^ (srow >> 3)) & 3);
  const u16* ga = A + (size_t)(m0 + srow) * D_DIM + sch * 8;
  const u16* gb = Ball + (size_t)(n0g + srow) * D_DIM + sch * 8;

  const f32x4 zero4 = {0.f, 0.f, 0.f, 0.f};
  f32x4 acc[4][6];
#pragma unroll
  for (int m = 0; m < 4; ++m)
#pragma unroll
    for (int n = 0; n < 6; ++n) acc[m][n] = zero4;

  for (int k0 = 0; k0 < D_DIM; k0 += 32) {
    load_lds16(ga + k0, &lA[t * 8]);
    load_lds16(ga + (size_t)64 * D_DIM + k0, &lA[2048 + t * 8]);
    load_lds16(gb + k0, &lB[t * 8]);
    load_lds16(gb + (size_t)64 * D_DIM + k0, &lB[2048 + t * 8]);
    load_lds16(gb + (size_t)128 * D_DIM + k0, &lB[4096 + t * 8]);
    __syncthreads();
    short8 af[4], bfr[6];
#pragma unroll
    for (int m = 0; m < 4; ++m) {
      const int R = wr * 64 + m * 16 + lo;
      af[m] = *(const short8*)&lA[R * 32 + ((g ^ ((R ^ (R >> 3)) & 3)) << 3)];
    }
#pragma unroll
    for (int n = 0; n < 6; ++n) {
      const int R = wc * 96 + n * 16 + lo;
      bfr[n] = *(const short8*)&lB[R * 32 + ((g ^ ((R ^ (R >> 3)) & 3)) << 3)];
    }
#pragma unroll
    for (int m = 0; m < 4; ++m)
#pragma unroll
      for (int n = 0; n < 6; ++n) acc[m][n] = MFMA16(af[m], bfr[n], acc[m][n]);
    __syncthreads();
  }

#pragma unroll
  for (int m = 0; m < 4; ++m) {
    const int row = m0 + wr * 64 + m * 16 + 4 * g;
#pragma unroll
    for (int n = 0; n < 6; ++n) {
      const int col_g = n0g + wc * 96 + n * 16 + lo;
      const int seg_c = col_g >> 11, c = col_g & 2047;
      u16* D = QKV + (size_t)seg_c * S_LEN * D_DIM;
      const float bb = bias_all[col_g];
#pragma unroll
      for (int r = 0; r < 4; ++r)
        D[(size_t)(row + r) * D_DIM + c] = f2bf(acc[m][n][r] + bb);
    }
  }
}

// ---------------- 128x128 GEMM body, BK=32 (m97 pattern) for WO ----------------
__device__ __forceinline__ void gemm_body(const u16* __restrict__ A, const u16* __restrict__ B,
                                          int m0, int n0, int t, f32x4 (*acc)[4],
                                          u16* lA, u16* lB) {
  const int lane = t & 63, w = t >> 6, lo = lane & 15, g = lane >> 4;
  const int wr = w >> 1, wc = w & 1;
  const int srow = t >> 2;
  const int sch = (t & 3) ^ ((srow ^ (srow >> 3)) & 3);
  const u16* ga = A + (size_t)(m0 + srow) * D_DIM + sch * 8;
  const u16* gb = B + (size_t)(n0 + srow) * D_DIM + sch * 8;
  for (int k0 = 0; k0 < D_DIM; k0 += 32) {
    load_lds16(ga + k0, &lA[t * 8]);
    load_lds16(ga + (size_t)64 * D_DIM + k0, &lA[2048 + t * 8]);
    load_lds16(gb + k0, &lB[t * 8]);
    load_lds16(gb + (size_t)64 * D_DIM + k0, &lB[2048 + t * 8]);
    __syncthreads();
    short8 af[4], bfr[4];
#pragma unroll
    for (int m = 0; m < 4; ++m) {
      const int R = wr * 64 + m * 16 + lo;
      af[m] = *(const short8*)&lA[R * 32 + ((g ^ ((R ^ (R >> 3)) & 3)) << 3)];
    }
#pragma unroll
    for (int n = 0; n < 4; ++n) {
      const int R = wc * 64 + n * 16 + lo;
      bfr[n] = *(const short8*)&lB[R * 32 + ((g ^ ((R ^ (R >> 3)) & 3)) << 3)];
    }
#pragma unroll
    for (int m = 0; m < 4; ++m)
#pragma unroll
      for (int n = 0; n < 4; ++n) acc[m][n] = MFMA16(af[m], bfr[n], acc[m][n]);
    __syncthreads();
  }
}

// ---------------- WO GEMM: 384 blocks, A-resident XCD chunking, fp32 out ----------------
__global__ __launch_bounds__(256) void k_gemm_wo(const u16* __restrict__ A,
                                                 const u16* __restrict__ B,
                                                 const float* __restrict__ bias,
                                                 float* __restrict__ C) {
  __shared__ u16 lA[128 * 32];
  __shared__ u16 lB[128 * 32];
  const int id = blockIdx.x;
  const int xcd = id & 7, local = id >> 3;   // 48 per XCD
  const int m_idx = xcd * 3 + local / 16;
  const int n_idx = local % 16;
  const int m0 = m_idx * 128, n0 = n_idx * 128;
  const int t = threadIdx.x;
  const int lane = t & 63, w = t >> 6, lo = lane & 15, g = lane >> 4;
  const int wr = w >> 1, wc = w & 1;
  const f32x4 zero4 = {0.f, 0.f, 0.f, 0.f};
  f32x4 acc[4][4];
#pragma unroll
  for (int m = 0; m < 4; ++m)
#pragma unroll
    for (int n = 0; n < 4; ++n) acc[m][n] = zero4;
  gemm_body(A, B, m0, n0, t, acc, lA, lB);
#pragma unroll
  for (int m = 0; m < 4; ++m) {
    const int row = m0 + wr * 64 + m * 16 + 4 * g;
#pragma unroll
    for (int n = 0; n < 4; ++n) {
      const int col = n0 + wc * 64 + n * 16 + lo;
      const float bb = bias[col];
#pragma unroll
      for (int r = 0; r < 4; ++r)
        C[(size_t)(row + r) * 2048 + col] = acc[m][n][r] + bb;
    }
  }
}

// -------- fused aux: RMSNorm+RoPE (Q,K) AND V transpose, one launch --------
// blocks [0,6144): rms for (s = bid>>1, which = bid&1)
// blocks [6144,7680): 64x64 transpose tile
__global__ __launch_bounds__(256) void k_aux(const u16* __restrict__ Q0, const u16* __restrict__ K0,
                                             const u16* __restrict__ V0,
                                             const float* __restrict__ gq, const float* __restrict__ gk,
                                             const float* __restrict__ cosT, const float* __restrict__ sinT,
                                             u16* __restrict__ qo, u16* __restrict__ ko,
                                             u16* __restrict__ vT) {
  const int bid = blockIdx.x, t = threadIdx.x;
  if (bid < 2 * S_LEN) {
    const int s = bid >> 1, which = bid & 1;
    const u16* H = which ? K0 : Q0;
    const float* gain = which ? gk : gq;
    u16* out = which ? ko : qo;
    const short8 hv = *(const short8*)(H + (size_t)s * D_DIM + t * 8);
    float h[8];
#pragma unroll
    for (int j = 0; j < 8; ++j) h[j] = bf2f((u16)hv[j]);
    float ss = 0.f;
#pragma unroll
    for (int j = 0; j < 8; ++j) ss += h[j] * h[j];
#pragma unroll
    for (int off = 32; off > 0; off >>= 1) ss += __shfl_xor(ss, off);
    __shared__ float red[4];
    if ((t & 63) == 0) red[t >> 6] = ss;
    __syncthreads();
    ss = red[0] + red[1] + red[2] + red[3];
    const float rs = rsqrtf(ss * (1.f / D_DIM) + 1e-6f);
    const float4 g0 = *(const float4*)(gain + t * 8);
    const float4 g1 = *(const float4*)(gain + t * 8 + 4);
    float y[8];
    y[0] = h[0] * rs * g0.x; y[1] = h[1] * rs * g0.y;
    y[2] = h[2] * rs * g0.z; y[3] = h[3] * rs * g0.w;
    y[4] = h[4] * rs * g1.x; y[5] = h[5] * rs * g1.y;
    y[6] = h[6] * rs * g1.z; y[7] = h[7] * rs * g1.w;
    const int cbase = ((t * 8) & 127) >> 1;
    short8 o8;
#pragma unroll
    for (int i = 0; i < 4; ++i) {
      const float cs = cosT[s * 64 + cbase + i];
      const float sn = sinT[s * 64 + cbase + i];
      const float yr = y[2 * i] * cs - y[2 * i + 1] * sn;
      const float yi = y[2 * i] * sn + y[2 * i + 1] * cs;
      o8[2 * i] = (short)f2bf(yr);
      o8[2 * i + 1] = (short)f2bf(yi);
    }
    *(short8*)(out + (size_t)s * D_DIM + t * 8) = o8;
  } else {
    __shared__ u16 tile[64][72];
    const int idx = bid - 2 * S_LEN;
    const int s0 = (idx % 48) * 64, d0 = (idx / 48) * 64;
    const int r = t >> 3, c8 = (t & 7) * 8;
#pragma unroll
    for (int p = 0; p < 2; ++p) {
      short8 v = *(const short8*)&V0[(size_t)(s0 + r + p * 32) * D_DIM + d0 + c8];
#pragma unroll
      for (int j = 0; j < 8; ++j) tile[r + p * 32][c8 + j] = (u16)v[j];
    }
    __syncthreads();
#pragma unroll
    for (int p = 0; p < 2; ++p) {
      const int dr = r + p * 32;
      short8 o;
#pragma unroll
      for (int j = 0; j < 8; ++j) o[j] = (short)tile[c8 + j][dr];
      *(short8*)&vT[(size_t)(d0 + dr) * S_LEN + s0 + c8] = o;
    }
  }
}

// ------- banded flash attention: QBLK=128, dbuf staging, XCD-chunked grid (T1) -------
// Flat grid 768: xcd=id&7 owns heads {2*xcd, 2*xcd+1} (K+V for 2 heads = 3.2MB,
// L2-resident per XCD) x 24 qt x 2 z. Kernel body identical to proven attn5.
__global__ __launch_bounds__(256, 3) void k_attn5(const u16* __restrict__ Q,
                                                  const u16* __restrict__ Kmat,
                                                  const u16* __restrict__ Vt,
                                                  u16* __restrict__ Oa,
                                                  u16* __restrict__ Ob,
                                                  float* __restrict__ lbuf) {
  const int id = blockIdx.x;
  const int xcd = id & 7, local = id >> 3;          // 96 per XCD
  const int h = xcd * 2 + (local / 48);
  const int rr_ = local % 48;
  const int qt = rr_ >> 1, z = rr_ & 1;
  const int t = threadIdx.x, w = t >> 6, lane = t & 63, lo = lane & 15, g = lane >> 4;
  const int q0 = qt * 128;
  const int wrow = q0 + w * 32;
  const size_t hoff = (size_t)h * 128;

  __shared__ u16 lK[2][32 * 128];
  __shared__ u16 lV[2][128 * 32];
  __shared__ u16 ldsp[4][32][40];

  short8 qf[2][4];
#pragma unroll
  for (int m = 0; m < 2; ++m) {
    const u16* qp = Q + (size_t)(wrow + m * 16 + lo) * D_DIM + hoff + g * 8;
#pragma unroll
    for (int c = 0; c < 4; ++c) qf[m][c] = *(const short8*)(qp + c * 32);
  }

  const f32x4 zero4 = {0.f, 0.f, 0.f, 0.f};
  f32x4 oacc[2][8];
#pragma unroll
  for (int m = 0; m < 2; ++m)
#pragma unroll
    for (int ct = 0; ct < 8; ++ct) oacc[m][ct] = zero4;
  float lrun[2][4] = {{0.f, 0.f, 0.f, 0.f}, {0.f, 0.f, 0.f, 0.f}};

  int jlo = q0 - WIN; if (jlo < 0) jlo = 0;
  int jhi = q0 + 127 + WIN + 1; if (jhi > S_LEN) jhi = S_LEN;
  const int NT = (jhi - jlo) >> 5;
  const int it0 = z * (NT >> 1), it1 = it0 + (NT >> 1);

  const int krow = t >> 4,          kch  = (t & 15) ^ (krow & 7);
  const int krow1 = (t + 256) >> 4, kch1 = (t & 15) ^ (krow1 & 7);
  const int vrow = t >> 2,          vch  = (t & 3) ^ ((vrow >> 1) & 3);
  const int vrow1 = (t + 256) >> 2, vch1 = (t & 3) ^ ((vrow1 >> 1) & 3);

#define STAGE5(buf, jj)                                                                              \
  do {                                                                                               \
    load_lds16(Kmat + (size_t)((jj) + krow) * D_DIM + hoff + (kch << 3), &lK[buf][t * 8]);           \
    load_lds16(Kmat + (size_t)((jj) + krow1) * D_DIM + hoff + (kch1 << 3), &lK[buf][(t + 256) * 8]); \
    load_lds16(Vt + (size_t)(hoff + vrow) * S_LEN + (jj) + (vch << 3), &lV[buf][t * 8]);             \
    load_lds16(Vt + (size_t)(hoff + vrow1) * S_LEN + (jj) + (vch1 << 3), &lV[buf][(t + 256) * 8]);   \
  } while (0)

  STAGE5(0, jlo + (it0 << 5));
  __syncthreads();
  int cur = 0;
  for (int it = it0; it < it1; ++it) {
    const int j0 = jlo + (it << 5);
    if (it + 1 < it1) STAGE5(cur ^ 1, j0 + 32);

    f32x4 sc[2][2];
    sc[0][0] = zero4; sc[0][1] = zero4; sc[1][0] = zero4; sc[1][1] = zero4;
#pragma unroll
    for (int half = 0; half < 2; ++half) {
#pragma unroll
      for (int c = 0; c < 4; ++c) {
        const short8 kf = *(const short8*)
            &lK[cur][(half * 16 + lo) * 128 + (((g + 4 * c) ^ (lo & 7)) << 3)];
        sc[0][half] = MFMA16(qf[0][c], kf, sc[0][half]);
        sc[1][half] = MFMA16(qf[1][c], kf, sc[1][half]);
      }
    }

    const int dq = j0 - q0;
    const bool interior = (dq >= -640) && (dq <= 736);
#pragma unroll
    for (int m = 0; m < 2; ++m) {
#pragma unroll
      for (int r = 0; r < 4; ++r) {
        float a0 = fmaf(sc[m][0][r], INV_SQRT_HD, -M_SHIFT);
        float a1 = fmaf(sc[m][1][r], INV_SQRT_HD, -M_SHIFT);
        if (!interior) {
          const int dk = j0 + lo - (wrow + m * 16 + 4 * g + r);
          if (dk < -WIN || dk > WIN) a0 = -3e38f;
          if (dk + 16 < -WIN || dk + 16 > WIN) a1 = -3e38f;
        }
        const float p0 = __expf(a0);
        const float p1 = __expf(a1);
        lrun[m][r] += p0 + p1;
        ldsp[w][m * 16 + 4 * g + r][lo] = f2bf(p0);
        ldsp[w][m * 16 + 4 * g + r][16 + lo] = f2bf(p1);
      }
    }

    const short8 pf0 = *(const short8*)&ldsp[w][lo][g * 8];
    const short8 pf1 = *(const short8*)&ldsp[w][16 + lo][g * 8];
#pragma unroll
    for (int ct = 0; ct < 8; ++ct) {
      const short8 vf = *(const short8*)
          &lV[cur][(ct * 16 + lo) * 32 + ((g ^ ((lo >> 1) & 3)) << 3)];
      oacc[0][ct] = MFMA16(pf0, vf, oacc[0][ct]);
      oacc[1][ct] = MFMA16(pf1, vf, oacc[1][ct]);
    }
    __syncthreads();
    cur ^= 1;
  }
#undef STAGE5

#pragma unroll
  for (int off = 8; off > 0; off >>= 1)
#pragma unroll
    for (int m = 0; m < 2; ++m)
#pragma unroll
      for (int r = 0; r < 4; ++r) lrun[m][r] += __shfl_xor(lrun[m][r], off);

  u16* Op = z ? Ob : Oa;
#pragma unroll
  for (int m = 0; m < 2; ++m)
#pragma unroll
    for (int r = 0; r < 4; ++r) {
      const int row = wrow + m * 16 + 4 * g + r;
#pragma unroll
      for (int ct = 0; ct < 8; ++ct)
        Op[(size_t)row * D_DIM + hoff + ct * 16 + lo] = f2bf(oacc[m][ct][r]);
      if (lo == 0) lbuf[(size_t)z * S_LEN * 16 + (size_t)row * 16 + h] = lrun[m][r];
    }
}

// ---------------- combine: out = (Oa + Ob) / (la + lb), bf16 ----------------
__global__ __launch_bounds__(256) void k_combine(const u16* __restrict__ Oa,
                                                 const u16* __restrict__ Ob,
                                                 const float* __restrict__ lbuf,
                                                 u16* __restrict__ out) {
  const int i = blockIdx.x * 256 + threadIdx.x;
  const int s = i >> 8, d8 = (i & 255) * 8, h = d8 >> 7;
  const float la = lbuf[(size_t)s * 16 + h];
  const float lb = lbuf[(size_t)S_LEN * 16 + (size_t)s * 16 + h];
  const float inv = 1.f / (la + lb);
  const size_t base = (size_t)s * D_DIM + d8;
  const short8 a = *(const short8*)(Oa + base);
  const short8 b = *(const short8*)(Ob + base);
  short8 o;
#pragma unroll
  for (int j = 0; j < 8; ++j)
    o[j] = (short)f2bf((bf2f((u16)a[j]) + bf2f((u16)b[j])) * inv);
  *(short8*)(out + base) = o;
}

extern "C" void kernel_launch(void* const* d_in, const int* in_sizes, int n_in,
                              void* d_out, int out_size, void* d_ws, size_t ws_size,
                              hipStream_t stream) {
  const float* x    = (const float*)d_in[0];
  const float* wq   = (const float*)d_in[1];
  const float* bq   = (const float*)d_in[2];
  const float* wk   = (const float*)d_in[3];
  const float* bk   = (const float*)d_in[4];
  const float* wv   = (const float*)d_in[5];
  const float* bv   = (const float*)d_in[6];
  const float* wo   = (const float*)d_in[7];
  const float* bo   = (const float*)d_in[8];
  const float* gq   = (const float*)d_in[9];
  const float* gk   = (const float*)d_in[10];
  const float* cosT = (const float*)d_in[11];
  const float* sinT = (const float*)d_in[12];

  char* ws = (char*)d_ws;
  const size_t WB = (size_t)D_DIM * D_DIM * 2;  // 8.4 MB
  const size_t XB = (size_t)S_LEN * D_DIM * 2;  // 12.6 MB
  u16*   wq_bf = (u16*)(ws);                     // wq|wk|wv contiguous = B[6144][2048]
  u16*   wk_bf = (u16*)(ws + WB);
  u16*   wv_bf = (u16*)(ws + 2 * WB);
  u16*   wo_bf = (u16*)(ws + 3 * WB);
  u16*   x_bf  = (u16*)(ws + 4 * WB);
  u16*   Q0b   = (u16*)(ws + 4 * WB + XB);       // Q|K|V contiguous outputs
  u16*   K0b   = (u16*)(ws + 4 * WB + 2 * XB);
  u16*   V0b   = (u16*)(ws + 4 * WB + 3 * XB);
  float* lbuf  = (float*)(ws + 4 * WB + 4 * XB);              // 2*S*16 fp32
  float* bias_all = (float*)(ws + 4 * WB + 4 * XB + 512 * 1024);  // 6144 fp32
  // stream-ordered reuse:
  u16* q_bf = x_bf;              // x_bf dead after QKV GEMM
  u16* k_bf = wq_bf;             // weights bf16 dead after QKV GEMM (k_bf spans [0, XB))
  u16* vT   = (u16*)(ws + XB);   // [XB, 2XB) also dead weight region (ends before wo_bf)
  u16* Ob   = K0b;               // K0b dead after k_aux
  u16* Oa   = (u16*)d_out;       // scratch; overwritten by final GEMM
  u16* attn = V0b;               // V0b dead after k_aux (transpose)

  const int nw4 = (D_DIM * D_DIM) / 4;
  const int nx4 = (S_LEN * D_DIM) / 4;
  const int ncvt = nx4 + 4 * nw4 + 6144 / 4;
  k_cvt_all<<<ncvt / 256, 256, 0, stream>>>(
      x, wq, wk, wv, wo, bq, bk, bv, x_bf, wq_bf, wk_bf, wv_bf, wo_bf, bias_all, nx4, nw4);

  k_gemm_qkv<<<768, 256, 0, stream>>>(x_bf, wq_bf, bias_all, Q0b);

  k_aux<<<2 * S_LEN + 1536, 256, 0, stream>>>(Q0b, K0b, V0b, gq, gk, cosT, sinT, q_bf, k_bf, vT);

  k_attn5<<<768, 256, 0, stream>>>(q_bf, k_bf, vT, Oa, Ob, lbuf);
  k_combine<<<(S_LEN * D_DIM / 8) / 256, 256, 0, stream>>>(Oa, Ob, lbuf, attn);

  k_gemm_wo<<<384, 256, 0, stream>>>(attn, wo_bf, bo, (float*)d_out);
}